// Round 1
// baseline (2275.061 us; speedup 1.0000x reference)
//
#include <hip/hip_runtime.h>
#include <math.h>

#define S_LEN 2048
#define DIM   2048
#define NH    16
#define NKV   8
#define HD    128
#define SKETCH 64
#define KV_DIM 1024
#define INV_SQRT_HD 0.08838834764831845f

// ---------------------------------------------------------------------------
// Shared tiled-GEMM helper: C[m0..m0+63][0..63] = (1/64) * X[64x2048] @ S[2048x64]
// used for AS = x @ Sk / 64  (and AS_o = att @ So / 64)
// ---------------------------------------------------------------------------
__device__ __forceinline__ void as_tile(const float* __restrict__ Xb,
                                        const float* __restrict__ Sb,
                                        float* __restrict__ ASb, int m0,
                                        float (*As)[68], float (*Bs)[68]) {
  const int tid = threadIdx.x;
  const int tx = tid & 15, ty = tid >> 4;
  float acc[4][4] = {};
  for (int k0 = 0; k0 < DIM; k0 += 64) {
    for (int i = tid; i < 1024; i += 256) {
      int r = i >> 4, c = (i & 15) << 2;
      float4 v = *(const float4*)(Xb + (size_t)(m0 + r) * DIM + k0 + c);
      As[r][c] = v.x; As[r][c + 1] = v.y; As[r][c + 2] = v.z; As[r][c + 3] = v.w;
      float4 u = *(const float4*)(Sb + (size_t)(k0 + r) * SKETCH + c);
      Bs[r][c] = u.x; Bs[r][c + 1] = u.y; Bs[r][c + 2] = u.z; Bs[r][c + 3] = u.w;
    }
    __syncthreads();
#pragma unroll
    for (int kk = 0; kk < 64; ++kk) {
      float a[4], bb[4];
#pragma unroll
      for (int i = 0; i < 4; ++i) a[i] = As[ty * 4 + i][kk];
#pragma unroll
      for (int j = 0; j < 4; ++j) bb[j] = Bs[kk][tx * 4 + j];
#pragma unroll
      for (int i = 0; i < 4; ++i)
#pragma unroll
        for (int j = 0; j < 4; ++j) acc[i][j] += a[i] * bb[j];
    }
    __syncthreads();
  }
#pragma unroll
  for (int i = 0; i < 4; ++i)
#pragma unroll
    for (int j = 0; j < 4; ++j)
      ASb[(size_t)(m0 + ty * 4 + i) * SKETCH + tx * 4 + j] = acc[i][j] * (1.0f / 64.0f);
}

// AS for q,k,v in one launch: grid(32, 2, 3)
__global__ __launch_bounds__(256) void as_gemm3(
    const float* __restrict__ x,
    const float* __restrict__ Sq, const float* __restrict__ Sk, const float* __restrict__ Sv,
    float* __restrict__ ASq, float* __restrict__ ASk, float* __restrict__ ASv) {
  __shared__ float As[64][68], Bs[64][68];
  const int b = blockIdx.y, t = blockIdx.z;
  const float* Ss = (t == 0) ? Sq : (t == 1) ? Sk : Sv;
  float* AS = (t == 0) ? ASq : (t == 1) ? ASk : ASv;
  as_tile(x + (size_t)b * S_LEN * DIM, Ss + (size_t)b * DIM * SKETCH,
          AS + (size_t)b * S_LEN * SKETCH, blockIdx.x * 64, As, Bs);
}

// AS_o: grid(32, 2)
__global__ __launch_bounds__(256) void as_gemm1(
    const float* __restrict__ X, const float* __restrict__ Ss, float* __restrict__ AS) {
  __shared__ float As[64][68], Bs[64][68];
  const int b = blockIdx.y;
  as_tile(X + (size_t)b * S_LEN * DIM, Ss + (size_t)b * DIM * SKETCH,
          AS + (size_t)b * S_LEN * SKETCH, blockIdx.x * 64, As, Bs);
}

// ---------------------------------------------------------------------------
// SB[b][k][m] = sum_d S[b][d][k] * W[m][d]    grid(32, 8): y = t*2 + b
// ---------------------------------------------------------------------------
__global__ __launch_bounds__(256) void sb_gemm4(
    const float* __restrict__ Sq, const float* __restrict__ Sk,
    const float* __restrict__ Sv, const float* __restrict__ So,
    const float* __restrict__ wq, const float* __restrict__ wk,
    const float* __restrict__ wv, const float* __restrict__ wo,
    float* __restrict__ SBq, float* __restrict__ SBk,
    float* __restrict__ SBv, float* __restrict__ SBo) {
  const int y = blockIdx.y;
  const int t = y >> 1, b = y & 1;
  const int Mout = (t == 0 || t == 3) ? DIM : KV_DIM;
  const int n0 = blockIdx.x * 64;
  if (n0 >= Mout) return;
  const float* Ss = (t == 0) ? Sq : (t == 1) ? Sk : (t == 2) ? Sv : So;
  const float* W  = (t == 0) ? wq : (t == 1) ? wk : (t == 2) ? wv : wo;
  float* SB       = (t == 0) ? SBq : (t == 1) ? SBk : (t == 2) ? SBv : SBo;
  const float* Sb = Ss + (size_t)b * DIM * SKETCH;
  float* SBb = SB + (size_t)b * SKETCH * Mout;

  __shared__ float As[64][68];  // [d][k]
  __shared__ float Bs[64][68];  // [d][m]
  const int tid = threadIdx.x;
  const int tx = tid & 15, ty = tid >> 4;
  float acc[4][4] = {};
  for (int d0 = 0; d0 < DIM; d0 += 64) {
    for (int i = tid; i < 1024; i += 256) {
      int r = i >> 4, c = (i & 15) << 2;
      float4 v = *(const float4*)(Sb + (size_t)(d0 + r) * SKETCH + c);
      As[r][c] = v.x; As[r][c + 1] = v.y; As[r][c + 2] = v.z; As[r][c + 3] = v.w;
      float4 u = *(const float4*)(W + (size_t)(n0 + r) * DIM + d0 + c);
      Bs[c][r] = u.x; Bs[c + 1][r] = u.y; Bs[c + 2][r] = u.z; Bs[c + 3][r] = u.w;
    }
    __syncthreads();
#pragma unroll
    for (int dd = 0; dd < 64; ++dd) {
      float a[4], bb[4];
#pragma unroll
      for (int i = 0; i < 4; ++i) a[i] = As[dd][ty * 4 + i];
#pragma unroll
      for (int j = 0; j < 4; ++j) bb[j] = Bs[dd][tx * 4 + j];
#pragma unroll
      for (int i = 0; i < 4; ++i)
#pragma unroll
        for (int j = 0; j < 4; ++j) acc[i][j] += a[i] * bb[j];
    }
    __syncthreads();
  }
#pragma unroll
  for (int i = 0; i < 4; ++i)
#pragma unroll
    for (int j = 0; j < 4; ++j)
      SBb[(size_t)(ty * 4 + i) * Mout + n0 + tx * 4 + j] = acc[i][j];
}

// ---------------------------------------------------------------------------
// proj = AS @ SB  (K = 64, single tile); optional rope; write [b][h][s][hd]
// ---------------------------------------------------------------------------
__device__ __forceinline__ void proj_tile_compute(
    const float* __restrict__ ASb, const float* __restrict__ SBb, int Mout,
    int s0, int n0, float (*As)[68], float (*Bs)[68], float acc[4][4]) {
  const int tid = threadIdx.x;
  const int tx = tid & 15, ty = tid >> 4;
  for (int i = tid; i < 1024; i += 256) {
    int r = i >> 4, c = (i & 15) << 2;
    float4 v = *(const float4*)(ASb + (size_t)(s0 + r) * SKETCH + c);
    As[r][c] = v.x; As[r][c + 1] = v.y; As[r][c + 2] = v.z; As[r][c + 3] = v.w;
    float4 u = *(const float4*)(SBb + (size_t)r * Mout + n0 + c);
    Bs[r][c] = u.x; Bs[r][c + 1] = u.y; Bs[r][c + 2] = u.z; Bs[r][c + 3] = u.w;
  }
  __syncthreads();
#pragma unroll
  for (int kk = 0; kk < 64; ++kk) {
    float a[4], bb[4];
#pragma unroll
    for (int i = 0; i < 4; ++i) a[i] = As[ty * 4 + i][kk];
#pragma unroll
    for (int j = 0; j < 4; ++j) bb[j] = Bs[kk][tx * 4 + j];
#pragma unroll
    for (int i = 0; i < 4; ++i)
#pragma unroll
      for (int j = 0; j < 4; ++j) acc[i][j] += a[i] * bb[j];
  }
}

// grid(32, 64, 2): y<32 -> q tile y; y<48 -> k tile y-32; else v tile y-48
__global__ __launch_bounds__(256) void proj_all(
    const float* __restrict__ ASq, const float* __restrict__ ASk,
    const float* __restrict__ ASv,
    const float* __restrict__ SBq, const float* __restrict__ SBk,
    const float* __restrict__ SBv,
    const float* __restrict__ freqs,
    float* __restrict__ Qb, float* __restrict__ Kb, float* __restrict__ Vb) {
  __shared__ float As[64][68], Bs[64][68];
  const int b = blockIdx.z, y = blockIdx.y;
  const float *AS, *SB;
  float* OUT;
  int Mout, nh, mt;
  bool rope;
  if (y < 32)      { AS = ASq; SB = SBq; OUT = Qb; Mout = DIM;    nh = NH;  rope = true;  mt = y; }
  else if (y < 48) { AS = ASk; SB = SBk; OUT = Kb; Mout = KV_DIM; nh = NKV; rope = true;  mt = y - 32; }
  else             { AS = ASv; SB = SBv; OUT = Vb; Mout = KV_DIM; nh = NKV; rope = false; mt = y - 48; }
  const int s0 = blockIdx.x * 64, n0 = mt * 64;
  float acc[4][4] = {};
  proj_tile_compute(AS + (size_t)b * S_LEN * SKETCH, SB + (size_t)b * SKETCH * Mout,
                    Mout, s0, n0, As, Bs, acc);
  const int tid = threadIdx.x;
  const int tx = tid & 15, ty = tid >> 4;
#pragma unroll
  for (int i = 0; i < 4; ++i) {
    const int s = s0 + ty * 4 + i;
    float vals[4];
    if (rope) {
#pragma unroll
      for (int pj = 0; pj < 2; ++pj) {
        int m = n0 + tx * 4 + pj * 2;
        int p = (m & (HD - 1)) >> 1;
        float co = freqs[((size_t)s * 64 + p) * 2 + 0];
        float si = freqs[((size_t)s * 64 + p) * 2 + 1];
        float x0 = acc[i][pj * 2], x1 = acc[i][pj * 2 + 1];
        vals[pj * 2]     = x0 * si - x1 * co;
        vals[pj * 2 + 1] = x0 * co + x1 * si;
      }
    } else {
#pragma unroll
      for (int j = 0; j < 4; ++j) vals[j] = acc[i][j];
    }
#pragma unroll
    for (int j = 0; j < 4; ++j) {
      int m = n0 + tx * 4 + j;
      int h = m >> 7, hd = m & (HD - 1);
      OUT[(((size_t)b * nh + h) * S_LEN + s) * HD + hd] = vals[j];
    }
  }
}

// final: out[b][s][m], grid(32, 32, 2)
__global__ __launch_bounds__(256) void proj_plain(
    const float* __restrict__ ASo, const float* __restrict__ SBo,
    float* __restrict__ out) {
  __shared__ float As[64][68], Bs[64][68];
  const int b = blockIdx.z;
  const int s0 = blockIdx.x * 64, n0 = blockIdx.y * 64;
  float acc[4][4] = {};
  proj_tile_compute(ASo + (size_t)b * S_LEN * SKETCH, SBo + (size_t)b * SKETCH * DIM,
                    DIM, s0, n0, As, Bs, acc);
  const int tid = threadIdx.x;
  const int tx = tid & 15, ty = tid >> 4;
#pragma unroll
  for (int i = 0; i < 4; ++i)
#pragma unroll
    for (int j = 0; j < 4; ++j)
      out[((size_t)b * S_LEN + s0 + ty * 4 + i) * DIM + n0 + tx * 4 + j] = acc[i][j];
}

// ---------------------------------------------------------------------------
// Flash attention, fp32, causal, GQA. grid(64, 32): x = q-tile (32 rows), y = b*16+h
// ---------------------------------------------------------------------------
#define QT 32
#define KT 64
__global__ __launch_bounds__(256) void attn(
    const float* __restrict__ Q, const float* __restrict__ K,
    const float* __restrict__ V, float* __restrict__ O) {
  const int bh = blockIdx.y;
  const int b = bh >> 4, h = bh & 15, g = h >> 1;
  const int qt = blockIdx.x;
  const float* Qp = Q + ((size_t)(b * NH + h) * S_LEN + qt * QT) * HD;
  const float* Kp = K + (size_t)(b * NKV + g) * S_LEN * HD;
  const float* Vp = V + (size_t)(b * NKV + g) * S_LEN * HD;

  __shared__ float Qs[QT][129];
  __shared__ float KVs[KT][129];
  __shared__ float Ps[QT][KT + 1];
  __shared__ float row_m[QT], row_l[QT], row_a[QT];

  const int tid = threadIdx.x;
  const int tx = tid & 15, ty = tid >> 4;

  for (int i = tid; i < QT * 32; i += 256) {
    int r = i >> 5, c = (i & 31) << 2;
    float4 v = *(const float4*)(Qp + (size_t)r * HD + c);
    Qs[r][c] = v.x; Qs[r][c + 1] = v.y; Qs[r][c + 2] = v.z; Qs[r][c + 3] = v.w;
  }
  if (tid < QT) { row_m[tid] = -3.0e38f; row_l[tid] = 0.0f; }
  float o_acc[2][8] = {};
  const int nkt = ((qt * QT + QT - 1) >> 6) + 1;
  __syncthreads();

  for (int kt = 0; kt < nkt; ++kt) {
    // stage K
    for (int i = tid; i < KT * 32; i += 256) {
      int r = i >> 5, c = (i & 31) << 2;
      float4 v = *(const float4*)(Kp + ((size_t)kt * KT + r) * HD + c);
      KVs[r][c] = v.x; KVs[r][c + 1] = v.y; KVs[r][c + 2] = v.z; KVs[r][c + 3] = v.w;
    }
    __syncthreads();
    float sc[2][4] = {};
#pragma unroll 4
    for (int d = 0; d < HD; ++d) {
      float a0 = Qs[ty * 2][d], a1 = Qs[ty * 2 + 1][d];
#pragma unroll
      for (int j = 0; j < 4; ++j) {
        float bv = KVs[tx * 4 + j][d];
        sc[0][j] += a0 * bv;
        sc[1][j] += a1 * bv;
      }
    }
#pragma unroll
    for (int i2 = 0; i2 < 2; ++i2)
#pragma unroll
      for (int j = 0; j < 4; ++j) {
        int qg = qt * QT + ty * 2 + i2;
        int kg = kt * KT + tx * 4 + j;
        Ps[ty * 2 + i2][tx * 4 + j] = (kg <= qg) ? sc[i2][j] * INV_SQRT_HD : -1.0e30f;
      }
    __syncthreads();
    if (tid < QT) {
      int r = tid;
      float mold = row_m[r], mloc = -1.0e30f;
      for (int j = 0; j < KT; ++j) mloc = fmaxf(mloc, Ps[r][j]);
      float mnew = fmaxf(mold, mloc);
      float alpha = __expf(mold - mnew);
      float sum = 0.0f;
      for (int j = 0; j < KT; ++j) {
        float p = __expf(Ps[r][j] - mnew);
        Ps[r][j] = p;
        sum += p;
      }
      row_l[r] = row_l[r] * alpha + sum;
      row_m[r] = mnew;
      row_a[r] = alpha;
    }
    __syncthreads();
    // stage V (K no longer needed)
    for (int i = tid; i < KT * 32; i += 256) {
      int r = i >> 5, c = (i & 31) << 2;
      float4 v = *(const float4*)(Vp + ((size_t)kt * KT + r) * HD + c);
      KVs[r][c] = v.x; KVs[r][c + 1] = v.y; KVs[r][c + 2] = v.z; KVs[r][c + 3] = v.w;
    }
    __syncthreads();
    float a0 = row_a[ty * 2], a1 = row_a[ty * 2 + 1];
#pragma unroll
    for (int c = 0; c < 8; ++c) { o_acc[0][c] *= a0; o_acc[1][c] *= a1; }
    for (int j = 0; j < KT; ++j) {
      float p0 = Ps[ty * 2][j], p1 = Ps[ty * 2 + 1][j];
#pragma unroll
      for (int c = 0; c < 8; ++c) {
        float vv = KVs[j][c * 16 + tx];
        o_acc[0][c] += p0 * vv;
        o_acc[1][c] += p1 * vv;
      }
    }
    __syncthreads();
  }
  float inv0 = 1.0f / row_l[ty * 2], inv1 = 1.0f / row_l[ty * 2 + 1];
#pragma unroll
  for (int c = 0; c < 8; ++c) {
    int col = c * 16 + tx;
    size_t base = ((size_t)b * S_LEN + qt * QT + ty * 2) * DIM + h * HD + col;
    O[base] = o_acc[0][c] * inv0;
    O[base + DIM] = o_acc[1][c] * inv1;
  }
}

// ---------------------------------------------------------------------------
extern "C" void kernel_launch(void* const* d_in, const int* in_sizes, int n_in,
                              void* d_out, int out_size, void* d_ws, size_t ws_size,
                              hipStream_t stream) {
  const float* x     = (const float*)d_in[0];
  const float* wq    = (const float*)d_in[1];
  const float* wk    = (const float*)d_in[2];
  const float* wv    = (const float*)d_in[3];
  const float* wo    = (const float*)d_in[4];
  const float* Sq    = (const float*)d_in[5];
  const float* Sk    = (const float*)d_in[6];
  const float* Sv    = (const float*)d_in[7];
  const float* So    = (const float*)d_in[8];
  const float* freqs = (const float*)d_in[9];
  float* out = (float*)d_out;

  float* p = (float*)d_ws;
  float* Qb  = p;                p += (size_t)2 * NH  * S_LEN * HD;  // 8388608
  float* Kb  = p;                p += (size_t)2 * NKV * S_LEN * HD;  // 4194304
  float* Vb  = p;                p += (size_t)2 * NKV * S_LEN * HD;  // 4194304
  float* ATT = p;                p += (size_t)2 * S_LEN * DIM;       // 8388608
  float* ASq = p;                p += (size_t)2 * S_LEN * SKETCH;
  float* ASk = p;                p += (size_t)2 * S_LEN * SKETCH;
  float* ASv = p;                p += (size_t)2 * S_LEN * SKETCH;
  float* ASo = p;                p += (size_t)2 * S_LEN * SKETCH;
  float* SBq = p;                p += (size_t)2 * SKETCH * DIM;
  float* SBk = p;                p += (size_t)2 * SKETCH * KV_DIM;
  float* SBv = p;                p += (size_t)2 * SKETCH * KV_DIM;
  float* SBo = p;                p += (size_t)2 * SKETCH * DIM;

  hipLaunchKernelGGL(sb_gemm4, dim3(32, 8), dim3(256), 0, stream,
                     Sq, Sk, Sv, So, wq, wk, wv, wo, SBq, SBk, SBv, SBo);
  hipLaunchKernelGGL(as_gemm3, dim3(32, 2, 3), dim3(256), 0, stream,
                     x, Sq, Sk, Sv, ASq, ASk, ASv);
  hipLaunchKernelGGL(proj_all, dim3(32, 64, 2), dim3(256), 0, stream,
                     ASq, ASk, ASv, SBq, SBk, SBv, freqs, Qb, Kb, Vb);
  hipLaunchKernelGGL(attn, dim3(64, 32), dim3(256), 0, stream, Qb, Kb, Vb, ATT);
  hipLaunchKernelGGL(as_gemm1, dim3(32, 2), dim3(256), 0, stream, ATT, So, ASo);
  hipLaunchKernelGGL(proj_plain, dim3(32, 32, 2), dim3(256), 0, stream, ASo, SBo, out);
}

// Round 2
// 853.566 us; speedup vs baseline: 2.6654x; 2.6654x over previous
//
#include <hip/hip_runtime.h>
#include <math.h>

#define S_LEN 2048
#define DIM   2048
#define NH    16
#define NKV   8
#define HD    128
#define SKETCH 64
#define KV_DIM 1024
#define INV_SQRT_HD 0.08838834764831845f
// softmax in base-2: fold log2(e) into the score scale
#define SCALE (0.08838834764831845f * 1.4426950408889634f)

typedef __bf16 bf16x8 __attribute__((ext_vector_type(8)));
typedef float  f32x4  __attribute__((ext_vector_type(4)));

// ---------------------------------------------------------------------------
// Shared tiled-GEMM helper: C[m0..m0+63][0..63] = (1/64) * X[64x2048] @ S[2048x64]
// ---------------------------------------------------------------------------
__device__ __forceinline__ void as_tile(const float* __restrict__ Xb,
                                        const float* __restrict__ Sb,
                                        float* __restrict__ ASb, int m0,
                                        float (*As)[68], float (*Bs)[68]) {
  const int tid = threadIdx.x;
  const int tx = tid & 15, ty = tid >> 4;
  float acc[4][4] = {};
  for (int k0 = 0; k0 < DIM; k0 += 64) {
    for (int i = tid; i < 1024; i += 256) {
      int r = i >> 4, c = (i & 15) << 2;
      float4 v = *(const float4*)(Xb + (size_t)(m0 + r) * DIM + k0 + c);
      As[r][c] = v.x; As[r][c + 1] = v.y; As[r][c + 2] = v.z; As[r][c + 3] = v.w;
      float4 u = *(const float4*)(Sb + (size_t)(k0 + r) * SKETCH + c);
      Bs[r][c] = u.x; Bs[r][c + 1] = u.y; Bs[r][c + 2] = u.z; Bs[r][c + 3] = u.w;
    }
    __syncthreads();
#pragma unroll
    for (int kk = 0; kk < 64; ++kk) {
      float a[4], bb[4];
#pragma unroll
      for (int i = 0; i < 4; ++i) a[i] = As[ty * 4 + i][kk];
#pragma unroll
      for (int j = 0; j < 4; ++j) bb[j] = Bs[kk][tx * 4 + j];
#pragma unroll
      for (int i = 0; i < 4; ++i)
#pragma unroll
        for (int j = 0; j < 4; ++j) acc[i][j] += a[i] * bb[j];
    }
    __syncthreads();
  }
#pragma unroll
  for (int i = 0; i < 4; ++i)
#pragma unroll
    for (int j = 0; j < 4; ++j)
      ASb[(size_t)(m0 + ty * 4 + i) * SKETCH + tx * 4 + j] = acc[i][j] * (1.0f / 64.0f);
}

__global__ __launch_bounds__(256) void as_gemm3(
    const float* __restrict__ x,
    const float* __restrict__ Sq, const float* __restrict__ Sk, const float* __restrict__ Sv,
    float* __restrict__ ASq, float* __restrict__ ASk, float* __restrict__ ASv) {
  __shared__ float As[64][68], Bs[64][68];
  const int b = blockIdx.y, t = blockIdx.z;
  const float* Ss = (t == 0) ? Sq : (t == 1) ? Sk : Sv;
  float* AS = (t == 0) ? ASq : (t == 1) ? ASk : ASv;
  as_tile(x + (size_t)b * S_LEN * DIM, Ss + (size_t)b * DIM * SKETCH,
          AS + (size_t)b * S_LEN * SKETCH, blockIdx.x * 64, As, Bs);
}

__global__ __launch_bounds__(256) void as_gemm1(
    const float* __restrict__ X, const float* __restrict__ Ss, float* __restrict__ AS) {
  __shared__ float As[64][68], Bs[64][68];
  const int b = blockIdx.y;
  as_tile(X + (size_t)b * S_LEN * DIM, Ss + (size_t)b * DIM * SKETCH,
          AS + (size_t)b * S_LEN * SKETCH, blockIdx.x * 64, As, Bs);
}

// ---------------------------------------------------------------------------
// SB[b][k][m] = sum_d S[b][d][k] * W[m][d]    grid(32, 8): y = t*2 + b
// ---------------------------------------------------------------------------
__global__ __launch_bounds__(256) void sb_gemm4(
    const float* __restrict__ Sq, const float* __restrict__ Sk,
    const float* __restrict__ Sv, const float* __restrict__ So,
    const float* __restrict__ wq, const float* __restrict__ wk,
    const float* __restrict__ wv, const float* __restrict__ wo,
    float* __restrict__ SBq, float* __restrict__ SBk,
    float* __restrict__ SBv, float* __restrict__ SBo) {
  const int y = blockIdx.y;
  const int t = y >> 1, b = y & 1;
  const int Mout = (t == 0 || t == 3) ? DIM : KV_DIM;
  const int n0 = blockIdx.x * 64;
  if (n0 >= Mout) return;
  const float* Ss = (t == 0) ? Sq : (t == 1) ? Sk : (t == 2) ? Sv : So;
  const float* W  = (t == 0) ? wq : (t == 1) ? wk : (t == 2) ? wv : wo;
  float* SB       = (t == 0) ? SBq : (t == 1) ? SBk : (t == 2) ? SBv : SBo;
  const float* Sb = Ss + (size_t)b * DIM * SKETCH;
  float* SBb = SB + (size_t)b * SKETCH * Mout;

  __shared__ float As[64][68];  // [d][k]
  __shared__ float Bs[64][68];  // [d][m]
  const int tid = threadIdx.x;
  const int tx = tid & 15, ty = tid >> 4;
  float acc[4][4] = {};
  for (int d0 = 0; d0 < DIM; d0 += 64) {
    for (int i = tid; i < 1024; i += 256) {
      int r = i >> 4, c = (i & 15) << 2;
      float4 v = *(const float4*)(Sb + (size_t)(d0 + r) * SKETCH + c);
      As[r][c] = v.x; As[r][c + 1] = v.y; As[r][c + 2] = v.z; As[r][c + 3] = v.w;
      float4 u = *(const float4*)(W + (size_t)(n0 + r) * DIM + d0 + c);
      Bs[c][r] = u.x; Bs[c + 1][r] = u.y; Bs[c + 2][r] = u.z; Bs[c + 3][r] = u.w;
    }
    __syncthreads();
#pragma unroll
    for (int dd = 0; dd < 64; ++dd) {
      float a[4], bb[4];
#pragma unroll
      for (int i = 0; i < 4; ++i) a[i] = As[dd][ty * 4 + i];
#pragma unroll
      for (int j = 0; j < 4; ++j) bb[j] = Bs[dd][tx * 4 + j];
#pragma unroll
      for (int i = 0; i < 4; ++i)
#pragma unroll
        for (int j = 0; j < 4; ++j) acc[i][j] += a[i] * bb[j];
    }
    __syncthreads();
  }
#pragma unroll
  for (int i = 0; i < 4; ++i)
#pragma unroll
    for (int j = 0; j < 4; ++j)
      SBb[(size_t)(ty * 4 + i) * Mout + n0 + tx * 4 + j] = acc[i][j];
}

// ---------------------------------------------------------------------------
// proj = AS @ SB  (K = 64, single tile); rope; write bf16 (hi/lo for q,k)
// ---------------------------------------------------------------------------
__device__ __forceinline__ void proj_tile_compute(
    const float* __restrict__ ASb, const float* __restrict__ SBb, int Mout,
    int s0, int n0, float (*As)[68], float (*Bs)[68], float acc[4][4]) {
  const int tid = threadIdx.x;
  const int tx = tid & 15, ty = tid >> 4;
  for (int i = tid; i < 1024; i += 256) {
    int r = i >> 4, c = (i & 15) << 2;
    float4 v = *(const float4*)(ASb + (size_t)(s0 + r) * SKETCH + c);
    As[r][c] = v.x; As[r][c + 1] = v.y; As[r][c + 2] = v.z; As[r][c + 3] = v.w;
    float4 u = *(const float4*)(SBb + (size_t)r * Mout + n0 + c);
    Bs[r][c] = u.x; Bs[r][c + 1] = u.y; Bs[r][c + 2] = u.z; Bs[r][c + 3] = u.w;
  }
  __syncthreads();
#pragma unroll
  for (int kk = 0; kk < 64; ++kk) {
    float a[4], bb[4];
#pragma unroll
    for (int i = 0; i < 4; ++i) a[i] = As[ty * 4 + i][kk];
#pragma unroll
    for (int j = 0; j < 4; ++j) bb[j] = Bs[kk][tx * 4 + j];
#pragma unroll
    for (int i = 0; i < 4; ++i)
#pragma unroll
      for (int j = 0; j < 4; ++j) acc[i][j] += a[i] * bb[j];
  }
}

// grid(32, 64, 2): y<32 -> q tile y; y<48 -> k tile y-32; else v tile y-48
__global__ __launch_bounds__(256) void proj_all(
    const float* __restrict__ ASq, const float* __restrict__ ASk,
    const float* __restrict__ ASv,
    const float* __restrict__ SBq, const float* __restrict__ SBk,
    const float* __restrict__ SBv,
    const float* __restrict__ freqs,
    __bf16* __restrict__ Qh, __bf16* __restrict__ Ql,
    __bf16* __restrict__ Kh, __bf16* __restrict__ Kl,
    __bf16* __restrict__ Vb) {
  __shared__ float As[64][68], Bs[64][68];
  const int b = blockIdx.z, y = blockIdx.y;
  const float *AS, *SB;
  int Mout, nh, mt;
  if (y < 32)      { AS = ASq; SB = SBq; Mout = DIM;    nh = NH;  mt = y; }
  else if (y < 48) { AS = ASk; SB = SBk; Mout = KV_DIM; nh = NKV; mt = y - 32; }
  else             { AS = ASv; SB = SBv; Mout = KV_DIM; nh = NKV; mt = y - 48; }
  const int s0 = blockIdx.x * 64, n0 = mt * 64;
  float acc[4][4] = {};
  proj_tile_compute(AS + (size_t)b * S_LEN * SKETCH, SB + (size_t)b * SKETCH * Mout,
                    Mout, s0, n0, As, Bs, acc);
  const int tid = threadIdx.x;
  const int tx = tid & 15, ty = tid >> 4;
  if (y < 48) {
    __bf16* OH = (y < 32) ? Qh : Kh;
    __bf16* OL = (y < 32) ? Ql : Kl;
#pragma unroll
    for (int i = 0; i < 4; ++i) {
      const int s = s0 + ty * 4 + i;
      float vals[4];
#pragma unroll
      for (int pj = 0; pj < 2; ++pj) {
        int m = n0 + tx * 4 + pj * 2;
        int p = (m & (HD - 1)) >> 1;
        float co = freqs[((size_t)s * 64 + p) * 2 + 0];
        float si = freqs[((size_t)s * 64 + p) * 2 + 1];
        float x0 = acc[i][pj * 2], x1 = acc[i][pj * 2 + 1];
        vals[pj * 2]     = x0 * si - x1 * co;
        vals[pj * 2 + 1] = x0 * co + x1 * si;
      }
#pragma unroll
      for (int j = 0; j < 4; ++j) {
        int m = n0 + tx * 4 + j;
        int h = m >> 7, hd = m & (HD - 1);
        size_t idx = (((size_t)b * nh + h) * S_LEN + s) * HD + hd;
        float v = vals[j];
        __bf16 vh = (__bf16)v;
        OH[idx] = vh;
        OL[idx] = (__bf16)(v - (float)vh);
      }
    }
  } else {
#pragma unroll
    for (int i = 0; i < 4; ++i) {
      const int s = s0 + ty * 4 + i;
#pragma unroll
      for (int j = 0; j < 4; ++j) {
        int m = n0 + tx * 4 + j;
        int h = m >> 7, hd = m & (HD - 1);
        Vb[(((size_t)b * NKV + h) * S_LEN + s) * HD + hd] = (__bf16)acc[i][j];
      }
    }
  }
}

// final: out[b][s][m], grid(32, 32, 2)
__global__ __launch_bounds__(256) void proj_plain(
    const float* __restrict__ ASo, const float* __restrict__ SBo,
    float* __restrict__ out) {
  __shared__ float As[64][68], Bs[64][68];
  const int b = blockIdx.z;
  const int s0 = blockIdx.x * 64, n0 = blockIdx.y * 64;
  float acc[4][4] = {};
  proj_tile_compute(ASo + (size_t)b * S_LEN * SKETCH, SBo + (size_t)b * SKETCH * DIM,
                    DIM, s0, n0, As, Bs, acc);
  const int tid = threadIdx.x;
  const int tx = tid & 15, ty = tid >> 4;
#pragma unroll
  for (int i = 0; i < 4; ++i)
#pragma unroll
    for (int j = 0; j < 4; ++j)
      out[((size_t)b * S_LEN + s0 + ty * 4 + i) * DIM + n0 + tx * 4 + j] = acc[i][j];
}

// ---------------------------------------------------------------------------
// MFMA flash attention, bf16 with hi/lo-split QK^T, causal, GQA.
// grid(32, 32): x -> q-tile (64 rows, reversed), y = b*16 + h. 256 thr = 4 waves.
// Wave w handles q rows [qt*64 + 16w, +16).
// ---------------------------------------------------------------------------
#define QT 64
#define KT 64
#define KPAD 136   // K LDS row stride (elems): 272B = 17*16, frag reads 2-way
#define VPAD 72    // Vt LDS row stride: 144B = 9*16
#define PPAD 72

__global__ __launch_bounds__(256) void attn_mfma(
    const __bf16* __restrict__ Qh, const __bf16* __restrict__ Ql,
    const __bf16* __restrict__ Kh, const __bf16* __restrict__ Kl,
    const __bf16* __restrict__ V, float* __restrict__ O) {
  const int bh = blockIdx.y;
  const int b = bh >> 4, h = bh & 15, g = h >> 1;
  const int qt = 31 - blockIdx.x;  // long blocks dispatch first
  const int q0 = qt * QT;

  const int tid = threadIdx.x;
  const int ln = tid & 63, w = tid >> 6;
  const int l15 = ln & 15, quad = ln >> 4;

  __shared__ __bf16 Khs[KT][KPAD];
  __shared__ __bf16 Kls[KT][KPAD];
  __shared__ __bf16 Vts[HD][VPAD];        // transposed: [d][k]
  __shared__ __bf16 Ps[4][16][PPAD];      // per-wave P tile [qrow][k]

  const __bf16* Khp = Kh + (size_t)(b * NKV + g) * S_LEN * HD;
  const __bf16* Klp = Kl + (size_t)(b * NKV + g) * S_LEN * HD;
  const __bf16* Vp  = V  + (size_t)(b * NKV + g) * S_LEN * HD;

  // Q fragments (A-layout: m = l15, k = quad*8 + j + 32c), once per block
  bf16x8 qh[4], ql[4];
  {
    const size_t qrow = (size_t)(b * NH + h) * S_LEN + q0 + w * 16 + l15;
#pragma unroll
    for (int c = 0; c < 4; ++c) {
      qh[c] = *(const bf16x8*)(Qh + qrow * HD + quad * 8 + 32 * c);
      ql[c] = *(const bf16x8*)(Ql + qrow * HD + quad * 8 + 32 * c);
    }
  }

  float mrow[4], lrow[4];
#pragma unroll
  for (int r = 0; r < 4; ++r) { mrow[r] = -1.0e30f; lrow[r] = 0.0f; }
  f32x4 o[8];
#pragma unroll
  for (int d = 0; d < 8; ++d) o[d] = (f32x4){0.f, 0.f, 0.f, 0.f};

  const int nkt = qt + 1;
  for (int kt = 0; kt < nkt; ++kt) {
    const int k0 = kt * KT;
    // ---- stage Kh, Kl ([k][d], coalesced) ----
    for (int i = tid; i < 1024; i += 256) {
      int r = i >> 4, c = (i & 15) << 3;
      *(bf16x8*)&Khs[r][c] = *(const bf16x8*)(Khp + (size_t)(k0 + r) * HD + c);
      *(bf16x8*)&Kls[r][c] = *(const bf16x8*)(Klp + (size_t)(k0 + r) * HD + c);
    }
    // ---- stage V transposed ([d][k]) ----
    for (int i = tid; i < 1024; i += 256) {
      int k = i & 63, d0 = (i >> 6) << 3;
      bf16x8 v = *(const bf16x8*)(Vp + (size_t)(k0 + k) * HD + d0);
#pragma unroll
      for (int j = 0; j < 8; ++j) Vts[d0 + j][k] = v[j];
    }
    __syncthreads();

    // ---- S = Q K^T (hi/lo split: qh*kh + ql*kh + qh*kl), fp32 acc ----
    f32x4 sc[4];
#pragma unroll
    for (int nt = 0; nt < 4; ++nt) {
      f32x4 acc = (f32x4){0.f, 0.f, 0.f, 0.f};
#pragma unroll
      for (int c = 0; c < 4; ++c) {
        bf16x8 bh = *(const bf16x8*)&Khs[nt * 16 + l15][quad * 8 + 32 * c];
        bf16x8 bl = *(const bf16x8*)&Kls[nt * 16 + l15][quad * 8 + 32 * c];
        acc = __builtin_amdgcn_mfma_f32_16x16x32_bf16(qh[c], bh, acc, 0, 0, 0);
        acc = __builtin_amdgcn_mfma_f32_16x16x32_bf16(ql[c], bh, acc, 0, 0, 0);
        acc = __builtin_amdgcn_mfma_f32_16x16x32_bf16(qh[c], bl, acc, 0, 0, 0);
      }
      sc[nt] = acc;
    }
    // scale + causal mask (only needed on the diagonal tile kt == qt)
    if (kt == qt) {
#pragma unroll
      for (int nt = 0; nt < 4; ++nt)
#pragma unroll
        for (int r = 0; r < 4; ++r) {
          int kg = nt * 16 + l15;
          int qg = w * 16 + quad * 4 + r;
          sc[nt][r] = (kg <= qg) ? sc[nt][r] * SCALE : -1.0e30f;
        }
    } else {
#pragma unroll
      for (int nt = 0; nt < 4; ++nt)
#pragma unroll
        for (int r = 0; r < 4; ++r) sc[nt][r] *= SCALE;
    }

    // ---- online softmax (rows live across the 16 lanes of each quad) ----
    float mloc[4];
#pragma unroll
    for (int r = 0; r < 4; ++r)
      mloc[r] = fmaxf(fmaxf(sc[0][r], sc[1][r]), fmaxf(sc[2][r], sc[3][r]));
#pragma unroll
    for (int off = 1; off < 16; off <<= 1)
#pragma unroll
      for (int r = 0; r < 4; ++r)
        mloc[r] = fmaxf(mloc[r], __shfl_xor(mloc[r], off));
    float alpha[4];
#pragma unroll
    for (int r = 0; r < 4; ++r) {
      float mn = fmaxf(mrow[r], mloc[r]);
      alpha[r] = __builtin_amdgcn_exp2f(mrow[r] - mn);
      mrow[r] = mn;
    }
    float psum[4] = {0.f, 0.f, 0.f, 0.f};
#pragma unroll
    for (int nt = 0; nt < 4; ++nt)
#pragma unroll
      for (int r = 0; r < 4; ++r) {
        float p = __builtin_amdgcn_exp2f(sc[nt][r] - mrow[r]);
        psum[r] += p;
        Ps[w][quad * 4 + r][nt * 16 + l15] = (__bf16)p;
      }
#pragma unroll
    for (int off = 1; off < 16; off <<= 1)
#pragma unroll
      for (int r = 0; r < 4; ++r) psum[r] += __shfl_xor(psum[r], off);
#pragma unroll
    for (int r = 0; r < 4; ++r) lrow[r] = lrow[r] * alpha[r] + psum[r];
#pragma unroll
    for (int d = 0; d < 8; ++d)
#pragma unroll
      for (int r = 0; r < 4; ++r) o[d][r] *= alpha[r];

    // ---- O += P V  (A = P from LDS, B = Vt) ----
#pragma unroll
    for (int dt = 0; dt < 8; ++dt) {
      f32x4 acc = o[dt];
#pragma unroll
      for (int c2 = 0; c2 < 2; ++c2) {
        bf16x8 a = *(const bf16x8*)&Ps[w][l15][quad * 8 + 32 * c2];
        bf16x8 bv = *(const bf16x8*)&Vts[dt * 16 + l15][quad * 8 + 32 * c2];
        acc = __builtin_amdgcn_mfma_f32_16x16x32_bf16(a, bv, acc, 0, 0, 0);
      }
      o[dt] = acc;
    }
    __syncthreads();
  }

  // ---- epilogue: O /= l, write [b][s][h*HD+d] f32 ----
  float inv[4];
#pragma unroll
  for (int r = 0; r < 4; ++r) inv[r] = 1.0f / lrow[r];
#pragma unroll
  for (int dt = 0; dt < 8; ++dt)
#pragma unroll
    for (int r = 0; r < 4; ++r) {
      int s = q0 + w * 16 + quad * 4 + r;
      int d = dt * 16 + l15;
      O[((size_t)b * S_LEN + s) * DIM + h * HD + d] = o[dt][r] * inv[r];
    }
}

// ---------------------------------------------------------------------------
extern "C" void kernel_launch(void* const* d_in, const int* in_sizes, int n_in,
                              void* d_out, int out_size, void* d_ws, size_t ws_size,
                              hipStream_t stream) {
  const float* x     = (const float*)d_in[0];
  const float* wq    = (const float*)d_in[1];
  const float* wk    = (const float*)d_in[2];
  const float* wv    = (const float*)d_in[3];
  const float* wo    = (const float*)d_in[4];
  const float* Sq    = (const float*)d_in[5];
  const float* Sk    = (const float*)d_in[6];
  const float* Sv    = (const float*)d_in[7];
  const float* So    = (const float*)d_in[8];
  const float* freqs = (const float*)d_in[9];
  float* out = (float*)d_out;

  const size_t QE = (size_t)2 * NH  * S_LEN * HD;  // 8.39M elems
  const size_t KE = (size_t)2 * NKV * S_LEN * HD;  // 4.19M elems

  float* fp = (float*)d_ws;
  float* ATT = fp;  fp += (size_t)2 * S_LEN * DIM;
  float* ASq = fp;  fp += (size_t)2 * S_LEN * SKETCH;
  float* ASk = fp;  fp += (size_t)2 * S_LEN * SKETCH;
  float* ASv = fp;  fp += (size_t)2 * S_LEN * SKETCH;
  float* ASo = fp;  fp += (size_t)2 * S_LEN * SKETCH;
  float* SBq = fp;  fp += (size_t)2 * SKETCH * DIM;
  float* SBk = fp;  fp += (size_t)2 * SKETCH * KV_DIM;
  float* SBv = fp;  fp += (size_t)2 * SKETCH * KV_DIM;
  float* SBo = fp;  fp += (size_t)2 * SKETCH * DIM;
  __bf16* bp = (__bf16*)fp;
  __bf16* Qhb = bp; bp += QE;
  __bf16* Qlb = bp; bp += QE;
  __bf16* Khb = bp; bp += KE;
  __bf16* Klb = bp; bp += KE;
  __bf16* Vbb = bp; bp += KE;

  hipLaunchKernelGGL(sb_gemm4, dim3(32, 8), dim3(256), 0, stream,
                     Sq, Sk, Sv, So, wq, wk, wv, wo, SBq, SBk, SBv, SBo);
  hipLaunchKernelGGL(as_gemm3, dim3(32, 2, 3), dim3(256), 0, stream,
                     x, Sq, Sk, Sv, ASq, ASk, ASv);
  hipLaunchKernelGGL(proj_all, dim3(32, 64, 2), dim3(256), 0, stream,
                     ASq, ASk, ASv, SBq, SBk, SBv, freqs, Qhb, Qlb, Khb, Klb, Vbb);
  hipLaunchKernelGGL(attn_mfma, dim3(32, 32), dim3(256), 0, stream,
                     Qhb, Qlb, Khb, Klb, Vbb, ATT);
  hipLaunchKernelGGL(as_gemm1, dim3(32, 2), dim3(256), 0, stream, ATT, So, ASo);
  hipLaunchKernelGGL(proj_plain, dim3(32, 32, 2), dim3(256), 0, stream, ASo, SBo, out);
}

// Round 4
// 498.297 us; speedup vs baseline: 4.5657x; 1.7130x over previous
//
#include <hip/hip_runtime.h>
#include <math.h>

#define S_LEN 2048
#define DIM   2048
#define NH    16
#define NKV   8
#define HD    128
#define SKETCH 64
#define KV_DIM 1024
#define INV_SQRT_HD 0.08838834764831845f
// softmax in base-2: fold log2(e) into the score scale
#define SCALE (0.08838834764831845f * 1.4426950408889634f)

typedef _Float16 half8_t __attribute__((ext_vector_type(8)));
typedef __bf16   bf8_t   __attribute__((ext_vector_type(8)));
typedef __bf16   bf4_t   __attribute__((ext_vector_type(4)));
typedef float    f32x16_t __attribute__((ext_vector_type(16)));

// ---------------------------------------------------------------------------
// GPR-side reduction helpers (max over 32 lanes). DPP ctrl must be an ICE ->
// template parameter.
// ---------------------------------------------------------------------------
template <int CTRL>
__device__ __forceinline__ float fmax_dpp(float x) {
  int xi = __builtin_bit_cast(int, x);
  int yi = __builtin_amdgcn_mov_dpp(xi, CTRL, 0xf, 0xf, true);
  return fmaxf(x, __builtin_bit_cast(float, yi));
}
__device__ __forceinline__ float rowmax32(float x) {
  x = fmax_dpp<0xB1>(x);   // quad_perm [1,0,3,2]  (xor 1)
  x = fmax_dpp<0x4E>(x);   // quad_perm [2,3,0,1]  (xor 2)
  x = fmax_dpp<0x141>(x);  // row_half_mirror      (pairs 8-groups)
  x = fmax_dpp<0x140>(x);  // row_mirror           (pairs 16-groups)
  int xi = __builtin_bit_cast(int, x);
  int yi = __builtin_amdgcn_ds_swizzle(xi, 0x401F);  // xor 16
  return fmaxf(x, __builtin_bit_cast(float, yi));
}

// ---------------------------------------------------------------------------
// SB[b][k][m] = sum_d S[b][d][k] * W[m][d]    grid(32, 8): y = t*2 + b
// ---------------------------------------------------------------------------
__global__ __launch_bounds__(256) void sb_gemm4(
    const float* __restrict__ Sq, const float* __restrict__ Sk,
    const float* __restrict__ Sv, const float* __restrict__ So,
    const float* __restrict__ wq, const float* __restrict__ wk,
    const float* __restrict__ wv, const float* __restrict__ wo,
    float* __restrict__ SBq, float* __restrict__ SBk,
    float* __restrict__ SBv, float* __restrict__ SBo) {
  const int y = blockIdx.y;
  const int t = y >> 1, b = y & 1;
  const int Mout = (t == 0 || t == 3) ? DIM : KV_DIM;
  const int n0 = blockIdx.x * 64;
  if (n0 >= Mout) return;
  const float* Ss = (t == 0) ? Sq : (t == 1) ? Sk : (t == 2) ? Sv : So;
  const float* W  = (t == 0) ? wq : (t == 1) ? wk : (t == 2) ? wv : wo;
  float* SB       = (t == 0) ? SBq : (t == 1) ? SBk : (t == 2) ? SBv : SBo;
  const float* Sb = Ss + (size_t)b * DIM * SKETCH;
  float* SBb = SB + (size_t)b * SKETCH * Mout;

  __shared__ float As[64][68];  // [d][k]
  __shared__ float Bs[64][68];  // [d][m]
  const int tid = threadIdx.x;
  const int tx = tid & 15, ty = tid >> 4;
  float acc[4][4] = {};
  for (int d0 = 0; d0 < DIM; d0 += 64) {
    for (int i = tid; i < 1024; i += 256) {
      int r = i >> 4, c = (i & 15) << 2;
      float4 v = *(const float4*)(Sb + (size_t)(d0 + r) * SKETCH + c);
      As[r][c] = v.x; As[r][c + 1] = v.y; As[r][c + 2] = v.z; As[r][c + 3] = v.w;
      float4 u = *(const float4*)(W + (size_t)(n0 + r) * DIM + d0 + c);
      Bs[c][r] = u.x; Bs[c + 1][r] = u.y; Bs[c + 2][r] = u.z; Bs[c + 3][r] = u.w;
    }
    __syncthreads();
#pragma unroll
    for (int dd = 0; dd < 64; ++dd) {
      float a[4], bb[4];
#pragma unroll
      for (int i = 0; i < 4; ++i) a[i] = As[dd][ty * 4 + i];
#pragma unroll
      for (int j = 0; j < 4; ++j) bb[j] = Bs[dd][tx * 4 + j];
#pragma unroll
      for (int i = 0; i < 4; ++i)
#pragma unroll
        for (int j = 0; j < 4; ++j) acc[i][j] += a[i] * bb[j];
    }
    __syncthreads();
  }
#pragma unroll
  for (int i = 0; i < 4; ++i)
#pragma unroll
    for (int j = 0; j < 4; ++j)
      SBb[(size_t)(ty * 4 + i) * Mout + n0 + tx * 4 + j] = acc[i][j];
}

// ---------------------------------------------------------------------------
// as_mfma: OUT[row][64] += (1/64) * X[row][:] @ S[b][:][:]
// X flat [4096][2048], S [2][2048][64], OUT flat [4096][64] (pre-zeroed).
// bf16 hi/lo 3-pass MFMA (fp32-grade). grid(32 row-tiles, 8 K-chunks).
// ---------------------------------------------------------------------------
__global__ __launch_bounds__(256) void as_mfma(
    const float* __restrict__ X, const float* __restrict__ S,
    float* __restrict__ OUT) {
  const int rt = blockIdx.x, kc = blockIdx.y;
  const int row0 = rt * 128;
  const int bb = row0 >> 11;
  const float* Sb = S + (size_t)bb * DIM * SKETCH;
  const int tid = threadIdx.x, ln = tid & 63, w = tid >> 6;
  const int l31 = ln & 31, h32 = ln >> 5;

  __shared__ __bf16 Xh[128][72], Xl[128][72];
  __shared__ __bf16 Sth[64][72], Stl[64][72];  // transposed: [n][c]

  f32x16_t acc[2];
#pragma unroll
  for (int nt = 0; nt < 2; ++nt)
#pragma unroll
    for (int r = 0; r < 16; ++r) acc[nt][r] = 0.0f;

  const int kbeg = kc * 256;
  for (int k0 = kbeg; k0 < kbeg + 256; k0 += 64) {
    // stage X tile 128x64 as bf16 hi/lo
#pragma unroll
    for (int it = 0; it < 8; ++it) {
      int idx = tid + it * 256;
      int r = idx >> 4, c4 = (idx & 15) << 2;
      float4 v = *(const float4*)(X + (size_t)(row0 + r) * DIM + k0 + c4);
      bf4_t hx, lx;
      float vv[4] = {v.x, v.y, v.z, v.w};
#pragma unroll
      for (int j = 0; j < 4; ++j) {
        __bf16 hh = (__bf16)vv[j];
        hx[j] = hh; lx[j] = (__bf16)(vv[j] - (float)hh);
      }
      *(bf4_t*)&Xh[r][c4] = hx;
      *(bf4_t*)&Xl[r][c4] = lx;
    }
    // stage S^T tile 64x64
#pragma unroll
    for (int it = 0; it < 4; ++it) {
      int idx = tid + it * 256;
      int r = idx & 63, c4 = (idx >> 6) << 2;
      float4 v = *(const float4*)(Sb + (size_t)(k0 + r) * SKETCH + c4);
      float vv[4] = {v.x, v.y, v.z, v.w};
#pragma unroll
      for (int j = 0; j < 4; ++j) {
        __bf16 hh = (__bf16)vv[j];
        Sth[c4 + j][r] = hh;
        Stl[c4 + j][r] = (__bf16)(vv[j] - (float)hh);
      }
    }
    __syncthreads();
#pragma unroll
    for (int ks = 0; ks < 4; ++ks) {
      bf8_t ah = *(const bf8_t*)&Xh[w * 32 + l31][ks * 16 + h32 * 8];
      bf8_t al = *(const bf8_t*)&Xl[w * 32 + l31][ks * 16 + h32 * 8];
#pragma unroll
      for (int nt = 0; nt < 2; ++nt) {
        bf8_t bh_ = *(const bf8_t*)&Sth[nt * 32 + l31][ks * 16 + h32 * 8];
        bf8_t bl_ = *(const bf8_t*)&Stl[nt * 32 + l31][ks * 16 + h32 * 8];
        acc[nt] = __builtin_amdgcn_mfma_f32_32x32x16_bf16(ah, bh_, acc[nt], 0, 0, 0);
        acc[nt] = __builtin_amdgcn_mfma_f32_32x32x16_bf16(al, bh_, acc[nt], 0, 0, 0);
        acc[nt] = __builtin_amdgcn_mfma_f32_32x32x16_bf16(ah, bl_, acc[nt], 0, 0, 0);
      }
    }
    __syncthreads();
  }
#pragma unroll
  for (int nt = 0; nt < 2; ++nt)
#pragma unroll
    for (int r = 0; r < 16; ++r) {
      int row = row0 + w * 32 + (r & 3) + 8 * (r >> 2) + 4 * h32;
      atomicAdd(&OUT[(size_t)row * SKETCH + nt * 32 + l31],
                acc[nt][r] * (1.0f / 64.0f));
    }
}

// ---------------------------------------------------------------------------
// proj = AS @ SB  (K = 64, single tile); rope; write fp16 Q/K/V
// ---------------------------------------------------------------------------
__device__ __forceinline__ void proj_tile_compute(
    const float* __restrict__ ASb, const float* __restrict__ SBb, int Mout,
    int s0, int n0, float (*As)[68], float (*Bs)[68], float acc[4][4]) {
  const int tid = threadIdx.x;
  const int tx = tid & 15, ty = tid >> 4;
  for (int i = tid; i < 1024; i += 256) {
    int r = i >> 4, c = (i & 15) << 2;
    float4 v = *(const float4*)(ASb + (size_t)(s0 + r) * SKETCH + c);
    As[r][c] = v.x; As[r][c + 1] = v.y; As[r][c + 2] = v.z; As[r][c + 3] = v.w;
    float4 u = *(const float4*)(SBb + (size_t)r * Mout + n0 + c);
    Bs[r][c] = u.x; Bs[r][c + 1] = u.y; Bs[r][c + 2] = u.z; Bs[r][c + 3] = u.w;
  }
  __syncthreads();
#pragma unroll
  for (int kk = 0; kk < 64; ++kk) {
    float a[4], bb[4];
#pragma unroll
    for (int i = 0; i < 4; ++i) a[i] = As[ty * 4 + i][kk];
#pragma unroll
    for (int j = 0; j < 4; ++j) bb[j] = Bs[kk][tx * 4 + j];
#pragma unroll
    for (int i = 0; i < 4; ++i)
#pragma unroll
      for (int j = 0; j < 4; ++j) acc[i][j] += a[i] * bb[j];
  }
}

// grid(32, 64, 2): y<32 -> q tile y; y<48 -> k tile y-32; else v tile y-48
__global__ __launch_bounds__(256) void proj_all(
    const float* __restrict__ ASq, const float* __restrict__ ASk,
    const float* __restrict__ ASv,
    const float* __restrict__ SBq, const float* __restrict__ SBk,
    const float* __restrict__ SBv,
    const float* __restrict__ freqs,
    _Float16* __restrict__ Qf, _Float16* __restrict__ Kf,
    _Float16* __restrict__ Vf) {
  __shared__ float As[64][68], Bs[64][68];
  const int b = blockIdx.z, y = blockIdx.y;
  const float *AS, *SB;
  int Mout, nh, mt;
  if (y < 32)      { AS = ASq; SB = SBq; Mout = DIM;    nh = NH;  mt = y; }
  else if (y < 48) { AS = ASk; SB = SBk; Mout = KV_DIM; nh = NKV; mt = y - 32; }
  else             { AS = ASv; SB = SBv; Mout = KV_DIM; nh = NKV; mt = y - 48; }
  const int s0 = blockIdx.x * 64, n0 = mt * 64;
  float acc[4][4] = {};
  proj_tile_compute(AS + (size_t)b * S_LEN * SKETCH, SB + (size_t)b * SKETCH * Mout,
                    Mout, s0, n0, As, Bs, acc);
  const int tid = threadIdx.x;
  const int tx = tid & 15, ty = tid >> 4;
  if (y < 48) {
    _Float16* OUT = (y < 32) ? Qf : Kf;
#pragma unroll
    for (int i = 0; i < 4; ++i) {
      const int s = s0 + ty * 4 + i;
      float vals[4];
#pragma unroll
      for (int pj = 0; pj < 2; ++pj) {
        int m = n0 + tx * 4 + pj * 2;
        int p = (m & (HD - 1)) >> 1;
        float co = freqs[((size_t)s * 64 + p) * 2 + 0];
        float si = freqs[((size_t)s * 64 + p) * 2 + 1];
        float x0 = acc[i][pj * 2], x1 = acc[i][pj * 2 + 1];
        vals[pj * 2]     = x0 * si - x1 * co;
        vals[pj * 2 + 1] = x0 * co + x1 * si;
      }
#pragma unroll
      for (int j = 0; j < 4; ++j) {
        int m = n0 + tx * 4 + j;
        int h = m >> 7, hd = m & (HD - 1);
        OUT[(((size_t)b * nh + h) * S_LEN + s) * HD + hd] = (_Float16)vals[j];
      }
    }
  } else {
#pragma unroll
    for (int i = 0; i < 4; ++i) {
      const int s = s0 + ty * 4 + i;
#pragma unroll
      for (int j = 0; j < 4; ++j) {
        int m = n0 + tx * 4 + j;
        int h = m >> 7, hd = m & (HD - 1);
        Vf[(((size_t)b * NKV + h) * S_LEN + s) * HD + hd] = (_Float16)acc[i][j];
      }
    }
  }
}

// final: out[b][s][m], grid(32, 32, 2)
__global__ __launch_bounds__(256) void proj_plain(
    const float* __restrict__ ASo, const float* __restrict__ SBo,
    float* __restrict__ out) {
  __shared__ float As[64][68], Bs[64][68];
  const int b = blockIdx.z;
  const int s0 = blockIdx.x * 64, n0 = blockIdx.y * 64;
  float acc[4][4] = {};
  proj_tile_compute(ASo + (size_t)b * S_LEN * SKETCH, SBo + (size_t)b * SKETCH * DIM,
                    DIM, s0, n0, As, Bs, acc);
  const int tid = threadIdx.x;
  const int tx = tid & 15, ty = tid >> 4;
#pragma unroll
  for (int i = 0; i < 4; ++i)
#pragma unroll
    for (int j = 0; j < 4; ++j)
      out[((size_t)b * S_LEN + s0 + ty * 4 + i) * DIM + n0 + tx * 4 + j] = acc[i][j];
}

// ---------------------------------------------------------------------------
// MFMA flash attention, fp16, 32x32x16, causal, GQA.
// grid(16, 32): x -> q-tile (128 rows, longest-first), y = b*16 + h.
// 256 thr = 4 waves; wave w owns q rows [q0 + 32w, +32).
// l accumulated via MFMA against a register ones-fragment (col 0 of o5).
// ---------------------------------------------------------------------------
#define QTT 128
#define KTT 64
#define KP  136   // 272B row stride == 16 mod 128 -> conflict-free b128 frags
#define VP  72    // 144B
#define PP  72

__global__ __launch_bounds__(256, 2) void attn_mfma(
    const _Float16* __restrict__ Qf, const _Float16* __restrict__ Kf,
    const _Float16* __restrict__ Vf, float* __restrict__ O) {
  const int bh = blockIdx.y;
  const int b = bh >> 4, h = bh & 15, g = h >> 1;
  const int qt = 15 - (int)blockIdx.x;
  const int q0 = qt * QTT;

  const int tid = threadIdx.x;
  const int ln = tid & 63, w = tid >> 6;
  const int l31 = ln & 31, h32 = ln >> 5;

  __shared__ _Float16 Ks[KTT][KP];
  __shared__ _Float16 Vts[HD][VP];     // transposed: [d][k]
  __shared__ _Float16 Ps[4][32][PP];   // per-wave P tile [row][k]

  const _Float16* Kp = Kf + (size_t)(b * NKV + g) * S_LEN * HD;
  const _Float16* Vp = Vf + (size_t)(b * NKV + g) * S_LEN * HD;

  // Q A-frags (m = l31 within wave's 32 rows, k = ks*16 + h32*8 + j)
  half8_t qfr[8];
  {
    const size_t qrow = (size_t)(b * NH + h) * S_LEN + q0 + w * 32 + l31;
#pragma unroll
    for (int ks = 0; ks < 8; ++ks)
      qfr[ks] = *(const half8_t*)(Qf + qrow * HD + ks * 16 + h32 * 8);
  }
  // ones B-fragment: B[k][0] = 1 -> col 0 of the 5th accumulator = sum_k P
  half8_t ones;
#pragma unroll
  for (int j = 0; j < 8; ++j) ones[j] = (l31 == 0) ? (_Float16)1.0f : (_Float16)0.0f;

  float mrow[16];
  f32x16_t o[4], o5;
#pragma unroll
  for (int r = 0; r < 16; ++r) {
    mrow[r] = -1.0e30f;
    o5[r] = 0.0f;
#pragma unroll
    for (int dt = 0; dt < 4; ++dt) o[dt][r] = 0.0f;
  }

  const int wq_start = q0 + w * 32;
  const int nkt = 2 * qt + 2;
  for (int kt = 0; kt < nkt; ++kt) {
    const int k0 = kt * KTT;
    // ---- stage K ([k][d], coalesced b128) ----
#pragma unroll
    for (int it = 0; it < 4; ++it) {
      int i = tid + it * 256;
      int r = i >> 4, c = (i & 15) << 3;
      *(half8_t*)&Ks[r][c] = *(const half8_t*)(Kp + (size_t)(k0 + r) * HD + c);
    }
    // ---- stage V transposed ([d][k], 2B-stride writes) ----
#pragma unroll
    for (int it = 0; it < 4; ++it) {
      int i = tid + it * 256;
      int k = i & 63, d0 = (i >> 6) << 3;
      half8_t v = *(const half8_t*)(Vp + (size_t)(k0 + k) * HD + d0);
#pragma unroll
      for (int j = 0; j < 8; ++j) Vts[d0 + j][k] = v[j];
    }
    __syncthreads();

    if (k0 < wq_start + 32) {  // wave-uniform: this wave has live rows here
      // ---- S = Q K^T ----
      f32x16_t sc[2];
#pragma unroll
      for (int nt = 0; nt < 2; ++nt)
#pragma unroll
        for (int r = 0; r < 16; ++r) sc[nt][r] = 0.0f;
#pragma unroll
      for (int ks = 0; ks < 8; ++ks) {
#pragma unroll
        for (int nt = 0; nt < 2; ++nt) {
          half8_t bf = *(const half8_t*)&Ks[nt * 32 + l31][ks * 16 + h32 * 8];
          sc[nt] = __builtin_amdgcn_mfma_f32_32x32x16_f16(qfr[ks], bf, sc[nt], 0, 0, 0);
        }
      }
      // ---- scale + causal mask ----
      const bool needMask = (k0 + KTT > wq_start);
#pragma unroll
      for (int nt = 0; nt < 2; ++nt)
#pragma unroll
        for (int r = 0; r < 16; ++r) {
          int qg = wq_start + (r & 3) + 8 * (r >> 2) + 4 * h32;
          int kg = k0 + nt * 32 + l31;
          float s = sc[nt][r] * SCALE;
          sc[nt][r] = (!needMask || kg <= qg) ? s : -1.0e30f;
        }
      // ---- online softmax: max via DPP+swizzle, sum via ones-MFMA ----
      float alpha[16];
#pragma unroll
      for (int r = 0; r < 16; ++r) {
        float ml = rowmax32(fmaxf(sc[0][r], sc[1][r]));
        float mn = fmaxf(mrow[r], ml);
        alpha[r] = __builtin_amdgcn_exp2f(mrow[r] - mn);
        mrow[r] = mn;
      }
#pragma unroll
      for (int nt = 0; nt < 2; ++nt)
#pragma unroll
        for (int r = 0; r < 16; ++r) {
          float p = __builtin_amdgcn_exp2f(sc[nt][r] - mrow[r]);
          Ps[w][(r & 3) + 8 * (r >> 2) + 4 * h32][nt * 32 + l31] = (_Float16)p;
        }
#pragma unroll
      for (int r = 0; r < 16; ++r) {
        o5[r] *= alpha[r];
#pragma unroll
        for (int dt = 0; dt < 4; ++dt) o[dt][r] *= alpha[r];
      }
      // ---- O += P V ; o5 += P ones ----
#pragma unroll
      for (int ks = 0; ks < 4; ++ks) {
        half8_t pa = *(const half8_t*)&Ps[w][l31][ks * 16 + h32 * 8];
#pragma unroll
        for (int dt = 0; dt < 4; ++dt) {
          half8_t vb = *(const half8_t*)&Vts[dt * 32 + l31][ks * 16 + h32 * 8];
          o[dt] = __builtin_amdgcn_mfma_f32_32x32x16_f16(pa, vb, o[dt], 0, 0, 0);
        }
        o5 = __builtin_amdgcn_mfma_f32_32x32x16_f16(pa, ones, o5, 0, 0, 0);
      }
    }
    __syncthreads();
  }

  // ---- epilogue: l lives in col 0 of o5 (lanes l31==0 of each half) ----
  float inv[16];
#pragma unroll
  for (int r = 0; r < 16; ++r) {
    float l = __shfl(o5[r], (ln & 32));
    inv[r] = 1.0f / l;
  }
#pragma unroll
  for (int dt = 0; dt < 4; ++dt)
#pragma unroll
    for (int r = 0; r < 16; ++r) {
      int qg = wq_start + (r & 3) + 8 * (r >> 2) + 4 * h32;
      int d = dt * 32 + l31;
      O[((size_t)b * S_LEN + qg) * DIM + h * HD + d] = o[dt][r] * inv[r];
    }
}

// ---------------------------------------------------------------------------
extern "C" void kernel_launch(void* const* d_in, const int* in_sizes, int n_in,
                              void* d_out, int out_size, void* d_ws, size_t ws_size,
                              hipStream_t stream) {
  const float* x     = (const float*)d_in[0];
  const float* wq    = (const float*)d_in[1];
  const float* wk    = (const float*)d_in[2];
  const float* wv    = (const float*)d_in[3];
  const float* wo    = (const float*)d_in[4];
  const float* Sq    = (const float*)d_in[5];
  const float* Sk    = (const float*)d_in[6];
  const float* Sv    = (const float*)d_in[7];
  const float* So    = (const float*)d_in[8];
  const float* freqs = (const float*)d_in[9];
  float* out = (float*)d_out;

  const size_t AS_E = (size_t)2 * S_LEN * SKETCH;  // 262144

  float* fp = (float*)d_ws;
  float* ASq = fp;  fp += AS_E;
  float* ASk = fp;  fp += AS_E;
  float* ASv = fp;  fp += AS_E;
  float* ASo = fp;  fp += AS_E;
  float* SBq = fp;  fp += (size_t)2 * SKETCH * DIM;
  float* SBk = fp;  fp += (size_t)2 * SKETCH * KV_DIM;
  float* SBv = fp;  fp += (size_t)2 * SKETCH * KV_DIM;
  float* SBo = fp;  fp += (size_t)2 * SKETCH * DIM;
  float* ATT = fp;  fp += (size_t)2 * S_LEN * DIM;
  _Float16* hp = (_Float16*)fp;
  _Float16* Qfb = hp; hp += (size_t)2 * NH  * S_LEN * HD;
  _Float16* Kfb = hp; hp += (size_t)2 * NKV * S_LEN * HD;
  _Float16* Vfb = hp; hp += (size_t)2 * NKV * S_LEN * HD;

  // zero the four atomic-accumulated AS buffers (contiguous)
  (void)hipMemsetAsync(ASq, 0, 4 * AS_E * sizeof(float), stream);

  hipLaunchKernelGGL(sb_gemm4, dim3(32, 8), dim3(256), 0, stream,
                     Sq, Sk, Sv, So, wq, wk, wv, wo, SBq, SBk, SBv, SBo);
  hipLaunchKernelGGL(as_mfma, dim3(32, 8), dim3(256), 0, stream, x, Sq, ASq);
  hipLaunchKernelGGL(as_mfma, dim3(32, 8), dim3(256), 0, stream, x, Sk, ASk);
  hipLaunchKernelGGL(as_mfma, dim3(32, 8), dim3(256), 0, stream, x, Sv, ASv);
  hipLaunchKernelGGL(proj_all, dim3(32, 64, 2), dim3(256), 0, stream,
                     ASq, ASk, ASv, SBq, SBk, SBv, freqs, Qfb, Kfb, Vfb);
  hipLaunchKernelGGL(attn_mfma, dim3(16, 32), dim3(256), 0, stream,
                     Qfb, Kfb, Vfb, ATT);
  hipLaunchKernelGGL(as_mfma, dim3(32, 8), dim3(256), 0, stream, ATT, So, ASo);
  hipLaunchKernelGGL(proj_plain, dim3(32, 32, 2), dim3(256), 0, stream, ASo, SBo, out);
}

// Round 5
// 465.625 us; speedup vs baseline: 4.8860x; 1.0702x over previous
//
#include <hip/hip_runtime.h>
#include <math.h>

#define S_LEN 2048
#define DIM   2048
#define NH    16
#define NKV   8
#define HD    128
#define SKETCH 64
#define KV_DIM 1024
#define INV_SQRT_HD 0.08838834764831845f
// softmax in base-2: fold log2(e) into the score scale
#define SCALE (0.08838834764831845f * 1.4426950408889634f)

typedef _Float16 half8_t __attribute__((ext_vector_type(8)));
typedef __bf16   bf8_t   __attribute__((ext_vector_type(8)));
typedef __bf16   bf4_t   __attribute__((ext_vector_type(4)));
typedef float    f32x16_t __attribute__((ext_vector_type(16)));

// ---------------------------------------------------------------------------
// GPR-side reduction helpers (max over 32 lanes). DPP ctrl must be an ICE ->
// template parameter.
// ---------------------------------------------------------------------------
template <int CTRL>
__device__ __forceinline__ float fmax_dpp(float x) {
  int xi = __builtin_bit_cast(int, x);
  int yi = __builtin_amdgcn_mov_dpp(xi, CTRL, 0xf, 0xf, true);
  return fmaxf(x, __builtin_bit_cast(float, yi));
}
__device__ __forceinline__ float rowmax32(float x) {
  x = fmax_dpp<0xB1>(x);   // quad_perm [1,0,3,2]  (xor 1)
  x = fmax_dpp<0x4E>(x);   // quad_perm [2,3,0,1]  (xor 2)
  x = fmax_dpp<0x141>(x);  // row_half_mirror
  x = fmax_dpp<0x140>(x);  // row_mirror
  int xi = __builtin_bit_cast(int, x);
  int yi = __builtin_amdgcn_ds_swizzle(xi, 0x401F);  // xor 16
  return fmaxf(x, __builtin_bit_cast(float, yi));
}

// ---------------------------------------------------------------------------
// sb_mfma: SB_t[b][k][m] = sum_d S_t[b][d][k] * W_t[m][d]
// bf16 hi/lo 3-pass MFMA. grid(96): n-tiles of 64 across {q:32,k:16,v:16,o:32}.
// Block handles BOTH batches (W staged once). 4 waves: w>>1 = batch, w&1 = m-strip.
// ---------------------------------------------------------------------------
__global__ __launch_bounds__(256) void sb_mfma(
    const float* __restrict__ Sq, const float* __restrict__ Sk,
    const float* __restrict__ Sv, const float* __restrict__ So,
    const float* __restrict__ wq, const float* __restrict__ wk,
    const float* __restrict__ wv, const float* __restrict__ wo,
    float* __restrict__ SBq, float* __restrict__ SBk,
    float* __restrict__ SBv, float* __restrict__ SBo) {
  const int bt = blockIdx.x;
  const float *Ss, *W;
  float* SB;
  int Mout, n0;
  if (bt < 32)      { Ss = Sq; W = wq; SB = SBq; Mout = DIM;    n0 = bt * 64; }
  else if (bt < 48) { Ss = Sk; W = wk; SB = SBk; Mout = KV_DIM; n0 = (bt - 32) * 64; }
  else if (bt < 64) { Ss = Sv; W = wv; SB = SBv; Mout = KV_DIM; n0 = (bt - 48) * 64; }
  else              { Ss = So; W = wo; SB = SBo; Mout = DIM;    n0 = (bt - 64) * 64; }

  const int tid = threadIdx.x, ln = tid & 63, w = tid >> 6;
  const int l31 = ln & 31, h32 = ln >> 5;
  const int bw = w >> 1, mt = w & 1;

  __shared__ __bf16 Sth[2][64][72], Stl[2][64][72];  // [b][kk][d_local]
  __shared__ __bf16 Wh[64][72], Wl[64][72];          // [c][d_local]

  f32x16_t acc[2];
#pragma unroll
  for (int ns = 0; ns < 2; ++ns)
#pragma unroll
    for (int r = 0; r < 16; ++r) acc[ns][r] = 0.0f;

  for (int d0 = 0; d0 < DIM; d0 += 64) {
    // stage S^T for both batches: 2*64*64 elems -> 8 float4/thread
#pragma unroll
    for (int it = 0; it < 8; ++it) {
      int i = tid + it * 256;          // [0, 2048)
      int b2 = i >> 10;
      int rem = i & 1023;
      int d = rem >> 4, c4 = (rem & 15) << 2;
      float4 v = *(const float4*)(Ss + ((size_t)b2 * DIM + d0 + d) * SKETCH + c4);
      float vv[4] = {v.x, v.y, v.z, v.w};
#pragma unroll
      for (int j = 0; j < 4; ++j) {
        __bf16 hh = (__bf16)vv[j];
        Sth[b2][c4 + j][d] = hh;
        Stl[b2][c4 + j][d] = (__bf16)(vv[j] - (float)hh);
      }
    }
    // stage W tile 64x64 ([c][d], no transpose) -> 4 float4/thread
#pragma unroll
    for (int it = 0; it < 4; ++it) {
      int i = tid + it * 256;          // [0, 1024)
      int c = i >> 4, d4 = (i & 15) << 2;
      float4 v = *(const float4*)(W + (size_t)(n0 + c) * DIM + d0 + d4);
      bf4_t hx, lx;
      float vv[4] = {v.x, v.y, v.z, v.w};
#pragma unroll
      for (int j = 0; j < 4; ++j) {
        __bf16 hh = (__bf16)vv[j];
        hx[j] = hh; lx[j] = (__bf16)(vv[j] - (float)hh);
      }
      *(bf4_t*)&Wh[c][d4] = hx;
      *(bf4_t*)&Wl[c][d4] = lx;
    }
    __syncthreads();
#pragma unroll
    for (int ks = 0; ks < 4; ++ks) {
      bf8_t ah = *(const bf8_t*)&Sth[bw][mt * 32 + l31][ks * 16 + h32 * 8];
      bf8_t al = *(const bf8_t*)&Stl[bw][mt * 32 + l31][ks * 16 + h32 * 8];
#pragma unroll
      for (int ns = 0; ns < 2; ++ns) {
        bf8_t bh_ = *(const bf8_t*)&Wh[ns * 32 + l31][ks * 16 + h32 * 8];
        bf8_t bl_ = *(const bf8_t*)&Wl[ns * 32 + l31][ks * 16 + h32 * 8];
        acc[ns] = __builtin_amdgcn_mfma_f32_32x32x16_bf16(ah, bh_, acc[ns], 0, 0, 0);
        acc[ns] = __builtin_amdgcn_mfma_f32_32x32x16_bf16(al, bh_, acc[ns], 0, 0, 0);
        acc[ns] = __builtin_amdgcn_mfma_f32_32x32x16_bf16(ah, bl_, acc[ns], 0, 0, 0);
      }
    }
    __syncthreads();
  }
#pragma unroll
  for (int ns = 0; ns < 2; ++ns)
#pragma unroll
    for (int r = 0; r < 16; ++r) {
      int kk = mt * 32 + (r & 3) + 8 * (r >> 2) + 4 * h32;
      SB[((size_t)bw * SKETCH + kk) * Mout + n0 + ns * 32 + l31] = acc[ns][r];
    }
}

// ---------------------------------------------------------------------------
// as_mfma3: AS_t[row][64] += (1/64) * X[row][:] @ S_t[b][:][:] for t in {q,k,v}.
// X staged once per K-chunk; S buffers cycled (stage/sync/mfma/sync).
// grid(32 row-tiles, 8 K-chunks); atomics into pre-zeroed AS buffers.
// ---------------------------------------------------------------------------
__global__ __launch_bounds__(256) void as_mfma3(
    const float* __restrict__ X,
    const float* __restrict__ Sq, const float* __restrict__ Sk,
    const float* __restrict__ Sv,
    float* __restrict__ ASq, float* __restrict__ ASk,
    float* __restrict__ ASv) {
  const int rt = blockIdx.x, kc = blockIdx.y;
  const int row0 = rt * 128;
  const int bb = row0 >> 11;
  const int tid = threadIdx.x, ln = tid & 63, w = tid >> 6;
  const int l31 = ln & 31, h32 = ln >> 5;

  __shared__ __bf16 Xh[128][72], Xl[128][72];
  __shared__ __bf16 Sth[64][72], Stl[64][72];

  const float* Sp[3] = {Sq + (size_t)bb * DIM * SKETCH,
                        Sk + (size_t)bb * DIM * SKETCH,
                        Sv + (size_t)bb * DIM * SKETCH};
  float* Op[3] = {ASq, ASk, ASv};

  f32x16_t acc[3][2];
#pragma unroll
  for (int t = 0; t < 3; ++t)
#pragma unroll
    for (int nt = 0; nt < 2; ++nt)
#pragma unroll
      for (int r = 0; r < 16; ++r) acc[t][nt][r] = 0.0f;

  const int kbeg = kc * 256;
  for (int k0 = kbeg; k0 < kbeg + 256; k0 += 64) {
    // stage X tile 128x64 hi/lo (once per K-chunk)
#pragma unroll
    for (int it = 0; it < 8; ++it) {
      int idx = tid + it * 256;
      int r = idx >> 4, c4 = (idx & 15) << 2;
      float4 v = *(const float4*)(X + (size_t)(row0 + r) * DIM + k0 + c4);
      bf4_t hx, lx;
      float vv[4] = {v.x, v.y, v.z, v.w};
#pragma unroll
      for (int j = 0; j < 4; ++j) {
        __bf16 hh = (__bf16)vv[j];
        hx[j] = hh; lx[j] = (__bf16)(vv[j] - (float)hh);
      }
      *(bf4_t*)&Xh[r][c4] = hx;
      *(bf4_t*)&Xl[r][c4] = lx;
    }
#pragma unroll
    for (int t = 0; t < 3; ++t) {
      // stage S_t^T tile 64x64
#pragma unroll
      for (int it = 0; it < 4; ++it) {
        int idx = tid + it * 256;
        int r = idx & 63, c4 = (idx >> 6) << 2;
        float4 v = *(const float4*)(Sp[t] + (size_t)(k0 + r) * SKETCH + c4);
        float vv[4] = {v.x, v.y, v.z, v.w};
#pragma unroll
        for (int j = 0; j < 4; ++j) {
          __bf16 hh = (__bf16)vv[j];
          Sth[c4 + j][r] = hh;
          Stl[c4 + j][r] = (__bf16)(vv[j] - (float)hh);
        }
      }
      __syncthreads();
#pragma unroll
      for (int ks = 0; ks < 4; ++ks) {
        bf8_t ah = *(const bf8_t*)&Xh[w * 32 + l31][ks * 16 + h32 * 8];
        bf8_t al = *(const bf8_t*)&Xl[w * 32 + l31][ks * 16 + h32 * 8];
#pragma unroll
        for (int nt = 0; nt < 2; ++nt) {
          bf8_t bh_ = *(const bf8_t*)&Sth[nt * 32 + l31][ks * 16 + h32 * 8];
          bf8_t bl_ = *(const bf8_t*)&Stl[nt * 32 + l31][ks * 16 + h32 * 8];
          acc[t][nt] = __builtin_amdgcn_mfma_f32_32x32x16_bf16(ah, bh_, acc[t][nt], 0, 0, 0);
          acc[t][nt] = __builtin_amdgcn_mfma_f32_32x32x16_bf16(al, bh_, acc[t][nt], 0, 0, 0);
          acc[t][nt] = __builtin_amdgcn_mfma_f32_32x32x16_bf16(ah, bl_, acc[t][nt], 0, 0, 0);
        }
      }
      __syncthreads();
    }
  }
#pragma unroll
  for (int t = 0; t < 3; ++t)
#pragma unroll
    for (int nt = 0; nt < 2; ++nt)
#pragma unroll
      for (int r = 0; r < 16; ++r) {
        int row = row0 + w * 32 + (r & 3) + 8 * (r >> 2) + 4 * h32;
        atomicAdd(&Op[t][(size_t)row * SKETCH + nt * 32 + l31],
                  acc[t][nt][r] * (1.0f / 64.0f));
      }
}

// ---------------------------------------------------------------------------
// as_mfma: single-matrix version (used for ATT @ So)
// ---------------------------------------------------------------------------
__global__ __launch_bounds__(256) void as_mfma(
    const float* __restrict__ X, const float* __restrict__ S,
    float* __restrict__ OUT) {
  const int rt = blockIdx.x, kc = blockIdx.y;
  const int row0 = rt * 128;
  const int bb = row0 >> 11;
  const float* Sb = S + (size_t)bb * DIM * SKETCH;
  const int tid = threadIdx.x, ln = tid & 63, w = tid >> 6;
  const int l31 = ln & 31, h32 = ln >> 5;

  __shared__ __bf16 Xh[128][72], Xl[128][72];
  __shared__ __bf16 Sth[64][72], Stl[64][72];

  f32x16_t acc[2];
#pragma unroll
  for (int nt = 0; nt < 2; ++nt)
#pragma unroll
    for (int r = 0; r < 16; ++r) acc[nt][r] = 0.0f;

  const int kbeg = kc * 256;
  for (int k0 = kbeg; k0 < kbeg + 256; k0 += 64) {
#pragma unroll
    for (int it = 0; it < 8; ++it) {
      int idx = tid + it * 256;
      int r = idx >> 4, c4 = (idx & 15) << 2;
      float4 v = *(const float4*)(X + (size_t)(row0 + r) * DIM + k0 + c4);
      bf4_t hx, lx;
      float vv[4] = {v.x, v.y, v.z, v.w};
#pragma unroll
      for (int j = 0; j < 4; ++j) {
        __bf16 hh = (__bf16)vv[j];
        hx[j] = hh; lx[j] = (__bf16)(vv[j] - (float)hh);
      }
      *(bf4_t*)&Xh[r][c4] = hx;
      *(bf4_t*)&Xl[r][c4] = lx;
    }
#pragma unroll
    for (int it = 0; it < 4; ++it) {
      int idx = tid + it * 256;
      int r = idx & 63, c4 = (idx >> 6) << 2;
      float4 v = *(const float4*)(Sb + (size_t)(k0 + r) * SKETCH + c4);
      float vv[4] = {v.x, v.y, v.z, v.w};
#pragma unroll
      for (int j = 0; j < 4; ++j) {
        __bf16 hh = (__bf16)vv[j];
        Sth[c4 + j][r] = hh;
        Stl[c4 + j][r] = (__bf16)(vv[j] - (float)hh);
      }
    }
    __syncthreads();
#pragma unroll
    for (int ks = 0; ks < 4; ++ks) {
      bf8_t ah = *(const bf8_t*)&Xh[w * 32 + l31][ks * 16 + h32 * 8];
      bf8_t al = *(const bf8_t*)&Xl[w * 32 + l31][ks * 16 + h32 * 8];
#pragma unroll
      for (int nt = 0; nt < 2; ++nt) {
        bf8_t bh_ = *(const bf8_t*)&Sth[nt * 32 + l31][ks * 16 + h32 * 8];
        bf8_t bl_ = *(const bf8_t*)&Stl[nt * 32 + l31][ks * 16 + h32 * 8];
        acc[nt] = __builtin_amdgcn_mfma_f32_32x32x16_bf16(ah, bh_, acc[nt], 0, 0, 0);
        acc[nt] = __builtin_amdgcn_mfma_f32_32x32x16_bf16(al, bh_, acc[nt], 0, 0, 0);
        acc[nt] = __builtin_amdgcn_mfma_f32_32x32x16_bf16(ah, bl_, acc[nt], 0, 0, 0);
      }
    }
    __syncthreads();
  }
#pragma unroll
  for (int nt = 0; nt < 2; ++nt)
#pragma unroll
    for (int r = 0; r < 16; ++r) {
      int row = row0 + w * 32 + (r & 3) + 8 * (r >> 2) + 4 * h32;
      atomicAdd(&OUT[(size_t)row * SKETCH + nt * 32 + l31],
                acc[nt][r] * (1.0f / 64.0f));
    }
}

// ---------------------------------------------------------------------------
// proj = AS @ SB  (K = 64, single tile); rope; write fp16 Q/K/V
// ---------------------------------------------------------------------------
__device__ __forceinline__ void proj_tile_compute(
    const float* __restrict__ ASb, const float* __restrict__ SBb, int Mout,
    int s0, int n0, float (*As)[68], float (*Bs)[68], float acc[4][4]) {
  const int tid = threadIdx.x;
  const int tx = tid & 15, ty = tid >> 4;
  for (int i = tid; i < 1024; i += 256) {
    int r = i >> 4, c = (i & 15) << 2;
    float4 v = *(const float4*)(ASb + (size_t)(s0 + r) * SKETCH + c);
    As[r][c] = v.x; As[r][c + 1] = v.y; As[r][c + 2] = v.z; As[r][c + 3] = v.w;
    float4 u = *(const float4*)(SBb + (size_t)r * Mout + n0 + c);
    Bs[r][c] = u.x; Bs[r][c + 1] = u.y; Bs[r][c + 2] = u.z; Bs[r][c + 3] = u.w;
  }
  __syncthreads();
#pragma unroll
  for (int kk = 0; kk < 64; ++kk) {
    float a[4], bb[4];
#pragma unroll
    for (int i = 0; i < 4; ++i) a[i] = As[ty * 4 + i][kk];
#pragma unroll
    for (int j = 0; j < 4; ++j) bb[j] = Bs[kk][tx * 4 + j];
#pragma unroll
    for (int i = 0; i < 4; ++i)
#pragma unroll
      for (int j = 0; j < 4; ++j) acc[i][j] += a[i] * bb[j];
  }
}

// grid(32, 64, 2): y<32 -> q tile y; y<48 -> k tile y-32; else v tile y-48
__global__ __launch_bounds__(256) void proj_all(
    const float* __restrict__ ASq, const float* __restrict__ ASk,
    const float* __restrict__ ASv,
    const float* __restrict__ SBq, const float* __restrict__ SBk,
    const float* __restrict__ SBv,
    const float* __restrict__ freqs,
    _Float16* __restrict__ Qf, _Float16* __restrict__ Kf,
    _Float16* __restrict__ Vf) {
  __shared__ float As[64][68], Bs[64][68];
  const int b = blockIdx.z, y = blockIdx.y;
  const float *AS, *SB;
  int Mout, nh, mt;
  if (y < 32)      { AS = ASq; SB = SBq; Mout = DIM;    nh = NH;  mt = y; }
  else if (y < 48) { AS = ASk; SB = SBk; Mout = KV_DIM; nh = NKV; mt = y - 32; }
  else             { AS = ASv; SB = SBv; Mout = KV_DIM; nh = NKV; mt = y - 48; }
  const int s0 = blockIdx.x * 64, n0 = mt * 64;
  float acc[4][4] = {};
  proj_tile_compute(AS + (size_t)b * S_LEN * SKETCH, SB + (size_t)b * SKETCH * Mout,
                    Mout, s0, n0, As, Bs, acc);
  const int tid = threadIdx.x;
  const int tx = tid & 15, ty = tid >> 4;
  if (y < 48) {
    _Float16* OUT = (y < 32) ? Qf : Kf;
#pragma unroll
    for (int i = 0; i < 4; ++i) {
      const int s = s0 + ty * 4 + i;
      float vals[4];
#pragma unroll
      for (int pj = 0; pj < 2; ++pj) {
        int m = n0 + tx * 4 + pj * 2;
        int p = (m & (HD - 1)) >> 1;
        float co = freqs[((size_t)s * 64 + p) * 2 + 0];
        float si = freqs[((size_t)s * 64 + p) * 2 + 1];
        float x0 = acc[i][pj * 2], x1 = acc[i][pj * 2 + 1];
        vals[pj * 2]     = x0 * si - x1 * co;
        vals[pj * 2 + 1] = x0 * co + x1 * si;
      }
#pragma unroll
      for (int j = 0; j < 4; ++j) {
        int m = n0 + tx * 4 + j;
        int h = m >> 7, hd = m & (HD - 1);
        OUT[(((size_t)b * nh + h) * S_LEN + s) * HD + hd] = (_Float16)vals[j];
      }
    }
  } else {
#pragma unroll
    for (int i = 0; i < 4; ++i) {
      const int s = s0 + ty * 4 + i;
#pragma unroll
      for (int j = 0; j < 4; ++j) {
        int m = n0 + tx * 4 + j;
        int h = m >> 7, hd = m & (HD - 1);
        Vf[(((size_t)b * NKV + h) * S_LEN + s) * HD + hd] = (_Float16)acc[i][j];
      }
    }
  }
}

// final: out[b][s][m], grid(32, 32, 2)
__global__ __launch_bounds__(256) void proj_plain(
    const float* __restrict__ ASo, const float* __restrict__ SBo,
    float* __restrict__ out) {
  __shared__ float As[64][68], Bs[64][68];
  const int b = blockIdx.z;
  const int s0 = blockIdx.x * 64, n0 = blockIdx.y * 64;
  float acc[4][4] = {};
  proj_tile_compute(ASo + (size_t)b * S_LEN * SKETCH, SBo + (size_t)b * SKETCH * DIM,
                    DIM, s0, n0, As, Bs, acc);
  const int tid = threadIdx.x;
  const int tx = tid & 15, ty = tid >> 4;
#pragma unroll
  for (int i = 0; i < 4; ++i)
#pragma unroll
    for (int j = 0; j < 4; ++j)
      out[((size_t)b * S_LEN + s0 + ty * 4 + i) * DIM + n0 + tx * 4 + j] = acc[i][j];
}

// ---------------------------------------------------------------------------
// MFMA flash attention, fp16, 32x32x16, causal, GQA. (unchanged)
// ---------------------------------------------------------------------------
#define QTT 128
#define KTT 64
#define KP  136
#define VP  72
#define PP  72

__global__ __launch_bounds__(256, 2) void attn_mfma(
    const _Float16* __restrict__ Qf, const _Float16* __restrict__ Kf,
    const _Float16* __restrict__ Vf, float* __restrict__ O) {
  const int bh = blockIdx.y;
  const int b = bh >> 4, h = bh & 15, g = h >> 1;
  const int qt = 15 - (int)blockIdx.x;
  const int q0 = qt * QTT;

  const int tid = threadIdx.x;
  const int ln = tid & 63, w = tid >> 6;
  const int l31 = ln & 31, h32 = ln >> 5;

  __shared__ _Float16 Ks[KTT][KP];
  __shared__ _Float16 Vts[HD][VP];
  __shared__ _Float16 Ps[4][32][PP];

  const _Float16* Kp = Kf + (size_t)(b * NKV + g) * S_LEN * HD;
  const _Float16* Vp = Vf + (size_t)(b * NKV + g) * S_LEN * HD;

  half8_t qfr[8];
  {
    const size_t qrow = (size_t)(b * NH + h) * S_LEN + q0 + w * 32 + l31;
#pragma unroll
    for (int ks = 0; ks < 8; ++ks)
      qfr[ks] = *(const half8_t*)(Qf + qrow * HD + ks * 16 + h32 * 8);
  }
  half8_t ones;
#pragma unroll
  for (int j = 0; j < 8; ++j) ones[j] = (l31 == 0) ? (_Float16)1.0f : (_Float16)0.0f;

  float mrow[16];
  f32x16_t o[4], o5;
#pragma unroll
  for (int r = 0; r < 16; ++r) {
    mrow[r] = -1.0e30f;
    o5[r] = 0.0f;
#pragma unroll
    for (int dt = 0; dt < 4; ++dt) o[dt][r] = 0.0f;
  }

  const int wq_start = q0 + w * 32;
  const int nkt = 2 * qt + 2;
  for (int kt = 0; kt < nkt; ++kt) {
    const int k0 = kt * KTT;
#pragma unroll
    for (int it = 0; it < 4; ++it) {
      int i = tid + it * 256;
      int r = i >> 4, c = (i & 15) << 3;
      *(half8_t*)&Ks[r][c] = *(const half8_t*)(Kp + (size_t)(k0 + r) * HD + c);
    }
#pragma unroll
    for (int it = 0; it < 4; ++it) {
      int i = tid + it * 256;
      int k = i & 63, d0 = (i >> 6) << 3;
      half8_t v = *(const half8_t*)(Vp + (size_t)(k0 + k) * HD + d0);
#pragma unroll
      for (int j = 0; j < 8; ++j) Vts[d0 + j][k] = v[j];
    }
    __syncthreads();

    if (k0 < wq_start + 32) {
      f32x16_t sc[2];
#pragma unroll
      for (int nt = 0; nt < 2; ++nt)
#pragma unroll
        for (int r = 0; r < 16; ++r) sc[nt][r] = 0.0f;
#pragma unroll
      for (int ks = 0; ks < 8; ++ks) {
#pragma unroll
        for (int nt = 0; nt < 2; ++nt) {
          half8_t bf = *(const half8_t*)&Ks[nt * 32 + l31][ks * 16 + h32 * 8];
          sc[nt] = __builtin_amdgcn_mfma_f32_32x32x16_f16(qfr[ks], bf, sc[nt], 0, 0, 0);
        }
      }
      const bool needMask = (k0 + KTT > wq_start);
#pragma unroll
      for (int nt = 0; nt < 2; ++nt)
#pragma unroll
        for (int r = 0; r < 16; ++r) {
          int qg = wq_start + (r & 3) + 8 * (r >> 2) + 4 * h32;
          int kg = k0 + nt * 32 + l31;
          float s = sc[nt][r] * SCALE;
          sc[nt][r] = (!needMask || kg <= qg) ? s : -1.0e30f;
        }
      float alpha[16];
#pragma unroll
      for (int r = 0; r < 16; ++r) {
        float ml = rowmax32(fmaxf(sc[0][r], sc[1][r]));
        float mn = fmaxf(mrow[r], ml);
        alpha[r] = __builtin_amdgcn_exp2f(mrow[r] - mn);
        mrow[r] = mn;
      }
#pragma unroll
      for (int nt = 0; nt < 2; ++nt)
#pragma unroll
        for (int r = 0; r < 16; ++r) {
          float p = __builtin_amdgcn_exp2f(sc[nt][r] - mrow[r]);
          Ps[w][(r & 3) + 8 * (r >> 2) + 4 * h32][nt * 32 + l31] = (_Float16)p;
        }
#pragma unroll
      for (int r = 0; r < 16; ++r) {
        o5[r] *= alpha[r];
#pragma unroll
        for (int dt = 0; dt < 4; ++dt) o[dt][r] *= alpha[r];
      }
#pragma unroll
      for (int ks = 0; ks < 4; ++ks) {
        half8_t pa = *(const half8_t*)&Ps[w][l31][ks * 16 + h32 * 8];
#pragma unroll
        for (int dt = 0; dt < 4; ++dt) {
          half8_t vb = *(const half8_t*)&Vts[dt * 32 + l31][ks * 16 + h32 * 8];
          o[dt] = __builtin_amdgcn_mfma_f32_32x32x16_f16(pa, vb, o[dt], 0, 0, 0);
        }
        o5 = __builtin_amdgcn_mfma_f32_32x32x16_f16(pa, ones, o5, 0, 0, 0);
      }
    }
    __syncthreads();
  }

  float inv[16];
#pragma unroll
  for (int r = 0; r < 16; ++r) {
    float l = __shfl(o5[r], (ln & 32));
    inv[r] = 1.0f / l;
  }
#pragma unroll
  for (int dt = 0; dt < 4; ++dt)
#pragma unroll
    for (int r = 0; r < 16; ++r) {
      int qg = wq_start + (r & 3) + 8 * (r >> 2) + 4 * h32;
      int d = dt * 32 + l31;
      O[((size_t)b * S_LEN + qg) * DIM + h * HD + d] = o[dt][r] * inv[r];
    }
}

// ---------------------------------------------------------------------------
extern "C" void kernel_launch(void* const* d_in, const int* in_sizes, int n_in,
                              void* d_out, int out_size, void* d_ws, size_t ws_size,
                              hipStream_t stream) {
  const float* x     = (const float*)d_in[0];
  const float* wq    = (const float*)d_in[1];
  const float* wk    = (const float*)d_in[2];
  const float* wv    = (const float*)d_in[3];
  const float* wo    = (const float*)d_in[4];
  const float* Sq    = (const float*)d_in[5];
  const float* Sk    = (const float*)d_in[6];
  const float* Sv    = (const float*)d_in[7];
  const float* So    = (const float*)d_in[8];
  const float* freqs = (const float*)d_in[9];
  float* out = (float*)d_out;

  const size_t AS_E = (size_t)2 * S_LEN * SKETCH;  // 262144

  float* fp = (float*)d_ws;
  float* ASq = fp;  fp += AS_E;
  float* ASk = fp;  fp += AS_E;
  float* ASv = fp;  fp += AS_E;
  float* ASo = fp;  fp += AS_E;
  float* SBq = fp;  fp += (size_t)2 * SKETCH * DIM;
  float* SBk = fp;  fp += (size_t)2 * SKETCH * KV_DIM;
  float* SBv = fp;  fp += (size_t)2 * SKETCH * KV_DIM;
  float* SBo = fp;  fp += (size_t)2 * SKETCH * DIM;
  float* ATT = fp;  fp += (size_t)2 * S_LEN * DIM;
  _Float16* hp = (_Float16*)fp;
  _Float16* Qfb = hp; hp += (size_t)2 * NH  * S_LEN * HD;
  _Float16* Kfb = hp; hp += (size_t)2 * NKV * S_LEN * HD;
  _Float16* Vfb = hp; hp += (size_t)2 * NKV * S_LEN * HD;

  // zero the four atomic-accumulated AS buffers (contiguous)
  (void)hipMemsetAsync(ASq, 0, 4 * AS_E * sizeof(float), stream);

  hipLaunchKernelGGL(sb_mfma, dim3(96), dim3(256), 0, stream,
                     Sq, Sk, Sv, So, wq, wk, wv, wo, SBq, SBk, SBv, SBo);
  hipLaunchKernelGGL(as_mfma3, dim3(32, 8), dim3(256), 0, stream,
                     x, Sq, Sk, Sv, ASq, ASk, ASv);
  hipLaunchKernelGGL(proj_all, dim3(32, 64, 2), dim3(256), 0, stream,
                     ASq, ASk, ASv, SBq, SBk, SBv, freqs, Qfb, Kfb, Vfb);
  hipLaunchKernelGGL(attn_mfma, dim3(16, 32), dim3(256), 0, stream,
                     Qfb, Kfb, Vfb, ATT);
  hipLaunchKernelGGL(as_mfma, dim3(32, 8), dim3(256), 0, stream, ATT, So, ASo);
  hipLaunchKernelGGL(proj_plain, dim3(32, 32, 2), dim3(256), 0, stream, ASo, SBo, out);
}

// Round 7
// 372.202 us; speedup vs baseline: 6.1124x; 1.2510x over previous
//
#include <hip/hip_runtime.h>
#include <math.h>

#define S_LEN 2048
#define DIM   2048
#define NH    16
#define NKV   8
#define HD    128
#define SKETCH 64
#define KV_DIM 1024
// softmax in base-2: fold log2(e) into the score scale
#define SCALE (0.08838834764831845f * 1.4426950408889634f)

typedef _Float16 half8_t  __attribute__((ext_vector_type(8)));
typedef __bf16   bf8_t    __attribute__((ext_vector_type(8)));
typedef __bf16   bf4_t    __attribute__((ext_vector_type(4)));
typedef float    f32x16_t __attribute__((ext_vector_type(16)));
typedef unsigned int uint4_t __attribute__((ext_vector_type(4)));

// ---------------------------------------------------------------------------
// Fused sb_mfma + as_mfma3.  grid(640):
//  x < 384: SB_t[b][k][m] = sum_d S_t[b][d][k] * W_t[m][d]  (atomicAdd, K-split 4)
//  x >= 384: AS_t[row][64] += (1/64) * X[row][:] @ S_t[b][:][:], t in {q,k,v}
// Both roles use the same 55296-byte LDS footprint.
// ---------------------------------------------------------------------------
__global__ __launch_bounds__(256) void sbas_mfma(
    const float* __restrict__ x,
    const float* __restrict__ Sq, const float* __restrict__ Sk,
    const float* __restrict__ Sv, const float* __restrict__ So,
    const float* __restrict__ wq, const float* __restrict__ wk,
    const float* __restrict__ wv, const float* __restrict__ wo,
    float* __restrict__ SBq, float* __restrict__ SBk,
    float* __restrict__ SBv, float* __restrict__ SBo,
    float* __restrict__ ASq, float* __restrict__ ASk,
    float* __restrict__ ASv) {
  __shared__ __align__(16) char smem[55296];
  const int tid = threadIdx.x, ln = tid & 63, w = tid >> 6;
  const int l31 = ln & 31, h32 = ln >> 5;
  const int bx = blockIdx.x;

  if (bx < 384) {
    // ---------------- SB role ----------------
    const int bt = bx % 96, kc = bx / 96;
    const float *Ss, *W;
    float* SB;
    int Mout, n0;
    if (bt < 32)      { Ss = Sq; W = wq; SB = SBq; Mout = DIM;    n0 = bt * 64; }
    else if (bt < 48) { Ss = Sk; W = wk; SB = SBk; Mout = KV_DIM; n0 = (bt - 32) * 64; }
    else if (bt < 64) { Ss = Sv; W = wv; SB = SBv; Mout = KV_DIM; n0 = (bt - 48) * 64; }
    else              { Ss = So; W = wo; SB = SBo; Mout = DIM;    n0 = (bt - 64) * 64; }

    __bf16* Sth = (__bf16*)smem;        // [2][64][72]
    __bf16* Stl = Sth + 9216;
    __bf16* Wh  = Stl + 9216;           // [64][72]
    __bf16* Wl  = Wh + 4608;

    const int bw = w >> 1, mt = w & 1;
    f32x16_t acc[2];
#pragma unroll
    for (int ns = 0; ns < 2; ++ns)
#pragma unroll
      for (int r = 0; r < 16; ++r) acc[ns][r] = 0.0f;

    const int dbeg = kc * 512;
    for (int d0 = dbeg; d0 < dbeg + 512; d0 += 64) {
#pragma unroll
      for (int it = 0; it < 8; ++it) {
        int i = tid + it * 256;
        int b2 = i >> 10, rem = i & 1023;
        int d = rem >> 4, c4 = (rem & 15) << 2;
        float4 v = *(const float4*)(Ss + ((size_t)b2 * DIM + d0 + d) * SKETCH + c4);
        float vv[4] = {v.x, v.y, v.z, v.w};
#pragma unroll
        for (int j = 0; j < 4; ++j) {
          __bf16 hh = (__bf16)vv[j];
          Sth[(b2 * 64 + c4 + j) * 72 + d] = hh;
          Stl[(b2 * 64 + c4 + j) * 72 + d] = (__bf16)(vv[j] - (float)hh);
        }
      }
#pragma unroll
      for (int it = 0; it < 4; ++it) {
        int i = tid + it * 256;
        int c = i >> 4, d4 = (i & 15) << 2;
        float4 v = *(const float4*)(W + (size_t)(n0 + c) * DIM + d0 + d4);
        bf4_t hx, lx;
        float vv[4] = {v.x, v.y, v.z, v.w};
#pragma unroll
        for (int j = 0; j < 4; ++j) {
          __bf16 hh = (__bf16)vv[j];
          hx[j] = hh; lx[j] = (__bf16)(vv[j] - (float)hh);
        }
        *(bf4_t*)&Wh[c * 72 + d4] = hx;
        *(bf4_t*)&Wl[c * 72 + d4] = lx;
      }
      __syncthreads();
#pragma unroll
      for (int ks = 0; ks < 4; ++ks) {
        bf8_t ah = *(const bf8_t*)&Sth[(bw * 64 + mt * 32 + l31) * 72 + ks * 16 + h32 * 8];
        bf8_t al = *(const bf8_t*)&Stl[(bw * 64 + mt * 32 + l31) * 72 + ks * 16 + h32 * 8];
#pragma unroll
        for (int ns = 0; ns < 2; ++ns) {
          bf8_t bh_ = *(const bf8_t*)&Wh[(ns * 32 + l31) * 72 + ks * 16 + h32 * 8];
          bf8_t bl_ = *(const bf8_t*)&Wl[(ns * 32 + l31) * 72 + ks * 16 + h32 * 8];
          acc[ns] = __builtin_amdgcn_mfma_f32_32x32x16_bf16(ah, bh_, acc[ns], 0, 0, 0);
          acc[ns] = __builtin_amdgcn_mfma_f32_32x32x16_bf16(al, bh_, acc[ns], 0, 0, 0);
          acc[ns] = __builtin_amdgcn_mfma_f32_32x32x16_bf16(ah, bl_, acc[ns], 0, 0, 0);
        }
      }
      __syncthreads();
    }
#pragma unroll
    for (int ns = 0; ns < 2; ++ns)
#pragma unroll
      for (int r = 0; r < 16; ++r) {
        int kk = mt * 32 + (r & 3) + 8 * (r >> 2) + 4 * h32;
        atomicAdd(&SB[((size_t)bw * SKETCH + kk) * Mout + n0 + ns * 32 + l31], acc[ns][r]);
      }
  } else {
    // ---------------- AS role ----------------
    const int idx = bx - 384;
    const int rt = idx >> 3, kc = idx & 7;
    const int row0 = rt * 128;
    const int bb = row0 >> 11;

    __bf16* Xh  = (__bf16*)smem;        // [128][72]
    __bf16* Xl  = Xh + 9216;
    __bf16* S2h = Xl + 9216;            // [64][72]
    __bf16* S2l = S2h + 4608;

    const float* Sp[3] = {Sq + (size_t)bb * DIM * SKETCH,
                          Sk + (size_t)bb * DIM * SKETCH,
                          Sv + (size_t)bb * DIM * SKETCH};
    float* Op[3] = {ASq, ASk, ASv};

    f32x16_t acc[3][2];
#pragma unroll
    for (int t = 0; t < 3; ++t)
#pragma unroll
      for (int nt = 0; nt < 2; ++nt)
#pragma unroll
        for (int r = 0; r < 16; ++r) acc[t][nt][r] = 0.0f;

    const int kbeg = kc * 256;
    for (int k0 = kbeg; k0 < kbeg + 256; k0 += 64) {
#pragma unroll
      for (int it = 0; it < 8; ++it) {
        int i = tid + it * 256;
        int r = i >> 4, c4 = (i & 15) << 2;
        float4 v = *(const float4*)(x + (size_t)(row0 + r) * DIM + k0 + c4);
        bf4_t hx, lx;
        float vv[4] = {v.x, v.y, v.z, v.w};
#pragma unroll
        for (int j = 0; j < 4; ++j) {
          __bf16 hh = (__bf16)vv[j];
          hx[j] = hh; lx[j] = (__bf16)(vv[j] - (float)hh);
        }
        *(bf4_t*)&Xh[r * 72 + c4] = hx;
        *(bf4_t*)&Xl[r * 72 + c4] = lx;
      }
#pragma unroll
      for (int t = 0; t < 3; ++t) {
#pragma unroll
        for (int it = 0; it < 4; ++it) {
          int i = tid + it * 256;
          int r = i & 63, c4 = (i >> 6) << 2;
          float4 v = *(const float4*)(Sp[t] + (size_t)(k0 + r) * SKETCH + c4);
          float vv[4] = {v.x, v.y, v.z, v.w};
#pragma unroll
          for (int j = 0; j < 4; ++j) {
            __bf16 hh = (__bf16)vv[j];
            S2h[(c4 + j) * 72 + r] = hh;
            S2l[(c4 + j) * 72 + r] = (__bf16)(vv[j] - (float)hh);
          }
        }
        __syncthreads();
#pragma unroll
        for (int ks = 0; ks < 4; ++ks) {
          bf8_t ah = *(const bf8_t*)&Xh[(w * 32 + l31) * 72 + ks * 16 + h32 * 8];
          bf8_t al = *(const bf8_t*)&Xl[(w * 32 + l31) * 72 + ks * 16 + h32 * 8];
#pragma unroll
          for (int nt = 0; nt < 2; ++nt) {
            bf8_t bh_ = *(const bf8_t*)&S2h[(nt * 32 + l31) * 72 + ks * 16 + h32 * 8];
            bf8_t bl_ = *(const bf8_t*)&S2l[(nt * 32 + l31) * 72 + ks * 16 + h32 * 8];
            acc[t][nt] = __builtin_amdgcn_mfma_f32_32x32x16_bf16(ah, bh_, acc[t][nt], 0, 0, 0);
            acc[t][nt] = __builtin_amdgcn_mfma_f32_32x32x16_bf16(al, bh_, acc[t][nt], 0, 0, 0);
            acc[t][nt] = __builtin_amdgcn_mfma_f32_32x32x16_bf16(ah, bl_, acc[t][nt], 0, 0, 0);
          }
        }
        __syncthreads();
      }
    }
#pragma unroll
    for (int t = 0; t < 3; ++t)
#pragma unroll
      for (int nt = 0; nt < 2; ++nt)
#pragma unroll
        for (int r = 0; r < 16; ++r) {
          int row = row0 + w * 32 + (r & 3) + 8 * (r >> 2) + 4 * h32;
          atomicAdd(&Op[t][(size_t)row * SKETCH + nt * 32 + l31],
                    acc[t][nt][r] * (1.0f / 64.0f));
        }
  }
}

// ---------------------------------------------------------------------------
// as_mfma: single-matrix version (ATT @ So), unchanged.
// ---------------------------------------------------------------------------
__global__ __launch_bounds__(256) void as_mfma(
    const float* __restrict__ X, const float* __restrict__ S,
    float* __restrict__ OUT) {
  const int rt = blockIdx.x, kc = blockIdx.y;
  const int row0 = rt * 128;
  const int bb = row0 >> 11;
  const float* Sb = S + (size_t)bb * DIM * SKETCH;
  const int tid = threadIdx.x, ln = tid & 63, w = tid >> 6;
  const int l31 = ln & 31, h32 = ln >> 5;

  __shared__ __bf16 Xh[128][72], Xl[128][72];
  __shared__ __bf16 Sth[64][72], Stl[64][72];

  f32x16_t acc[2];
#pragma unroll
  for (int nt = 0; nt < 2; ++nt)
#pragma unroll
    for (int r = 0; r < 16; ++r) acc[nt][r] = 0.0f;

  const int kbeg = kc * 256;
  for (int k0 = kbeg; k0 < kbeg + 256; k0 += 64) {
#pragma unroll
    for (int it = 0; it < 8; ++it) {
      int idx = tid + it * 256;
      int r = idx >> 4, c4 = (idx & 15) << 2;
      float4 v = *(const float4*)(X + (size_t)(row0 + r) * DIM + k0 + c4);
      bf4_t hx, lx;
      float vv[4] = {v.x, v.y, v.z, v.w};
#pragma unroll
      for (int j = 0; j < 4; ++j) {
        __bf16 hh = (__bf16)vv[j];
        hx[j] = hh; lx[j] = (__bf16)(vv[j] - (float)hh);
      }
      *(bf4_t*)&Xh[r][c4] = hx;
      *(bf4_t*)&Xl[r][c4] = lx;
    }
#pragma unroll
    for (int it = 0; it < 4; ++it) {
      int idx = tid + it * 256;
      int r = idx & 63, c4 = (idx >> 6) << 2;
      float4 v = *(const float4*)(Sb + (size_t)(k0 + r) * SKETCH + c4);
      float vv[4] = {v.x, v.y, v.z, v.w};
#pragma unroll
      for (int j = 0; j < 4; ++j) {
        __bf16 hh = (__bf16)vv[j];
        Sth[c4 + j][r] = hh;
        Stl[c4 + j][r] = (__bf16)(vv[j] - (float)hh);
      }
    }
    __syncthreads();
#pragma unroll
    for (int ks = 0; ks < 4; ++ks) {
      bf8_t ah = *(const bf8_t*)&Xh[w * 32 + l31][ks * 16 + h32 * 8];
      bf8_t al = *(const bf8_t*)&Xl[w * 32 + l31][ks * 16 + h32 * 8];
#pragma unroll
      for (int nt = 0; nt < 2; ++nt) {
        bf8_t bh_ = *(const bf8_t*)&Sth[nt * 32 + l31][ks * 16 + h32 * 8];
        bf8_t bl_ = *(const bf8_t*)&Stl[nt * 32 + l31][ks * 16 + h32 * 8];
        acc[nt] = __builtin_amdgcn_mfma_f32_32x32x16_bf16(ah, bh_, acc[nt], 0, 0, 0);
        acc[nt] = __builtin_amdgcn_mfma_f32_32x32x16_bf16(al, bh_, acc[nt], 0, 0, 0);
        acc[nt] = __builtin_amdgcn_mfma_f32_32x32x16_bf16(ah, bl_, acc[nt], 0, 0, 0);
      }
    }
    __syncthreads();
  }
#pragma unroll
  for (int nt = 0; nt < 2; ++nt)
#pragma unroll
    for (int r = 0; r < 16; ++r) {
      int row = row0 + w * 32 + (r & 3) + 8 * (r >> 2) + 4 * h32;
      atomicAdd(&OUT[(size_t)row * SKETCH + nt * 32 + l31],
                acc[nt][r] * (1.0f / 64.0f));
    }
}

// ---------------------------------------------------------------------------
// proj (MFMA, bf16 hi/lo): C[128 s][64 m] = AS[128x64] @ SB[64x Mout] tile.
// ---------------------------------------------------------------------------
__device__ __forceinline__ void proj_gemm_core(
    const float* __restrict__ ASb, const float* __restrict__ SBb, int Mout,
    int s0, int n0, __bf16* ASh, __bf16* ASl, __bf16* SBth, __bf16* SBtl,
    f32x16_t acc[2]) {
  const int tid = threadIdx.x, ln = tid & 63, w = tid >> 6;
  const int l31 = ln & 31, h32 = ln >> 5;
#pragma unroll
  for (int it = 0; it < 8; ++it) {
    int i = tid + it * 256;
    int r = i >> 4, c4 = (i & 15) << 2;
    float4 v = *(const float4*)(ASb + (size_t)(s0 + r) * SKETCH + c4);
    bf4_t hx, lx;
    float vv[4] = {v.x, v.y, v.z, v.w};
#pragma unroll
    for (int j = 0; j < 4; ++j) {
      __bf16 hh = (__bf16)vv[j];
      hx[j] = hh; lx[j] = (__bf16)(vv[j] - (float)hh);
    }
    *(bf4_t*)&ASh[r * 72 + c4] = hx;
    *(bf4_t*)&ASl[r * 72 + c4] = lx;
  }
#pragma unroll
  for (int it = 0; it < 4; ++it) {
    int i = tid + it * 256;
    int k = i >> 4, c4 = (i & 15) << 2;
    float4 v = *(const float4*)(SBb + (size_t)k * Mout + n0 + c4);
    float vv[4] = {v.x, v.y, v.z, v.w};
#pragma unroll
    for (int j = 0; j < 4; ++j) {
      __bf16 hh = (__bf16)vv[j];
      SBth[(c4 + j) * 72 + k] = hh;
      SBtl[(c4 + j) * 72 + k] = (__bf16)(vv[j] - (float)hh);
    }
  }
  __syncthreads();
#pragma unroll
  for (int ks = 0; ks < 4; ++ks) {
    bf8_t ah = *(const bf8_t*)&ASh[(w * 32 + l31) * 72 + ks * 16 + h32 * 8];
    bf8_t al = *(const bf8_t*)&ASl[(w * 32 + l31) * 72 + ks * 16 + h32 * 8];
#pragma unroll
    for (int nt = 0; nt < 2; ++nt) {
      bf8_t bh_ = *(const bf8_t*)&SBth[(nt * 32 + l31) * 72 + ks * 16 + h32 * 8];
      bf8_t bl_ = *(const bf8_t*)&SBtl[(nt * 32 + l31) * 72 + ks * 16 + h32 * 8];
      acc[nt] = __builtin_amdgcn_mfma_f32_32x32x16_bf16(ah, bh_, acc[nt], 0, 0, 0);
      acc[nt] = __builtin_amdgcn_mfma_f32_32x32x16_bf16(al, bh_, acc[nt], 0, 0, 0);
      acc[nt] = __builtin_amdgcn_mfma_f32_32x32x16_bf16(ah, bl_, acc[nt], 0, 0, 0);
    }
  }
}

// grid(16, 64, 2): y<32 q (rope), y<48 k (rope), else v. Writes fp16 [b][h][s][hd].
__global__ __launch_bounds__(256) void proj_qkv(
    const float* __restrict__ ASq, const float* __restrict__ ASk,
    const float* __restrict__ ASv,
    const float* __restrict__ SBq, const float* __restrict__ SBk,
    const float* __restrict__ SBv,
    const float* __restrict__ freqs,
    _Float16* __restrict__ Qf, _Float16* __restrict__ Kf,
    _Float16* __restrict__ Vf) {
  __shared__ __bf16 ASh[128 * 72], ASl[128 * 72], SBth[64 * 72], SBtl[64 * 72];
  const int b = blockIdx.z, y = blockIdx.y;
  const float *AS, *SB;
  int Mout, nh, mt;
  _Float16* OUT;
  bool rope;
  if (y < 32)      { AS = ASq; SB = SBq; Mout = DIM;    nh = NH;  mt = y;      OUT = Qf; rope = true; }
  else if (y < 48) { AS = ASk; SB = SBk; Mout = KV_DIM; nh = NKV; mt = y - 32; OUT = Kf; rope = true; }
  else             { AS = ASv; SB = SBv; Mout = KV_DIM; nh = NKV; mt = y - 48; OUT = Vf; rope = false; }
  const int s0 = blockIdx.x * 128, n0 = mt * 64;
  f32x16_t acc[2];
#pragma unroll
  for (int nt = 0; nt < 2; ++nt)
#pragma unroll
    for (int r = 0; r < 16; ++r) acc[nt][r] = 0.0f;
  proj_gemm_core(AS + (size_t)b * S_LEN * SKETCH, SB + (size_t)b * SKETCH * Mout,
                 Mout, s0, n0, ASh, ASl, SBth, SBtl, acc);
  const int tid = threadIdx.x, ln = tid & 63, w = tid >> 6;
  const int l31 = ln & 31, h32 = ln >> 5;
  const bool meven = (l31 & 1) == 0;
#pragma unroll
  for (int nt = 0; nt < 2; ++nt) {
    const int m = n0 + nt * 32 + l31;
    const int h = m >> 7, hd = m & (HD - 1);
    const int p = hd >> 1;
#pragma unroll
    for (int r = 0; r < 16; ++r) {
      const int s = s0 + w * 32 + (r & 3) + 8 * (r >> 2) + 4 * h32;
      float v = acc[nt][r];
      float outv;
      if (rope) {
        int pi = __builtin_bit_cast(int, v);
        float part = __builtin_bit_cast(float, __builtin_amdgcn_ds_swizzle(pi, 0x041F));
        float co = freqs[((size_t)s * 64 + p) * 2 + 0];
        float si = freqs[((size_t)s * 64 + p) * 2 + 1];
        outv = meven ? (v * si - part * co) : (part * co + v * si);
      } else {
        outv = v;
      }
      OUT[(((size_t)b * nh + h) * S_LEN + s) * HD + hd] = (_Float16)outv;
    }
  }
}

// grid(16, 32, 2): out[b][s][m] f32
__global__ __launch_bounds__(256) void proj_out(
    const float* __restrict__ ASo, const float* __restrict__ SBo,
    float* __restrict__ out) {
  __shared__ __bf16 ASh[128 * 72], ASl[128 * 72], SBth[64 * 72], SBtl[64 * 72];
  const int b = blockIdx.z;
  const int s0 = blockIdx.x * 128, n0 = blockIdx.y * 64;
  f32x16_t acc[2];
#pragma unroll
  for (int nt = 0; nt < 2; ++nt)
#pragma unroll
    for (int r = 0; r < 16; ++r) acc[nt][r] = 0.0f;
  proj_gemm_core(ASo + (size_t)b * S_LEN * SKETCH, SBo + (size_t)b * SKETCH * DIM,
                 DIM, s0, n0, ASh, ASl, SBth, SBtl, acc);
  const int tid = threadIdx.x, ln = tid & 63, w = tid >> 6;
  const int l31 = ln & 31, h32 = ln >> 5;
#pragma unroll
  for (int nt = 0; nt < 2; ++nt)
#pragma unroll
    for (int r = 0; r < 16; ++r) {
      const int s = s0 + w * 32 + (r & 3) + 8 * (r >> 2) + 4 * h32;
      out[((size_t)b * S_LEN + s) * DIM + n0 + nt * 32 + l31] = acc[nt][r];
    }
}

// ---------------------------------------------------------------------------
// MFMA flash attention v2: S^T formulation (lane = q-column softmax),
// register prefetch of K/V tiles, P^T exchanged in-register (no P LDS).
// grid(16, 32): x -> q-tile (128 rows, longest-first), y = b*16 + h.
// ---------------------------------------------------------------------------
#define QTT 128
#define KTT 64
#define KP  136   // halfs per K row (272 B)
#define VP  72    // halfs per Vt row (144 B)

__global__ __launch_bounds__(256, 2) void attn_mfma(
    const _Float16* __restrict__ Qf, const _Float16* __restrict__ Kf,
    const _Float16* __restrict__ Vf, float* __restrict__ O) {
  const int bh = blockIdx.y;
  const int b = bh >> 4, h = bh & 15, g = h >> 1;
  const int qt = 15 - (int)blockIdx.x;
  const int q0 = qt * QTT;

  const int tid = threadIdx.x;
  const int ln = tid & 63, w = tid >> 6;
  const int l31 = ln & 31, h32 = ln >> 5;
  const bool hb = (h32 != 0);

  __shared__ _Float16 Ks[KTT][KP];     // 17408 B
  __shared__ _Float16 Vts[HD][VP];     // 18432 B (epilogue overlay: float[128][36])
  float* Ot = (float*)&Vts[0][0];

  const _Float16* Kp = Kf + (size_t)(b * NKV + g) * S_LEN * HD;
  const _Float16* Vp = Vf + (size_t)(b * NKV + g) * S_LEN * HD;

  // Q fragments (B-operand for S^T; same lane mapping as A-operand)
  half8_t qfr[8];
  {
    const size_t qrow = (size_t)(b * NH + h) * S_LEN + q0 + w * 32 + l31;
#pragma unroll
    for (int ks = 0; ks < 8; ++ks)
      qfr[ks] = *(const half8_t*)(Qf + qrow * HD + ks * 16 + h32 * 8);
  }

  float mrow = -1.0e30f, lrow = 0.0f;
  f32x16_t o[4];
#pragma unroll
  for (int dt = 0; dt < 4; ++dt)
#pragma unroll
    for (int r = 0; r < 16; ++r) o[dt][r] = 0.0f;

  const int wq_start = q0 + w * 32;
  const int qq = wq_start + l31;
  const int nkt = 2 * qt + 2;

  half8_t kreg[4], vreg[4];
  // preload tile 0
#pragma unroll
  for (int it = 0; it < 4; ++it) {
    int i = tid + it * 256;
    kreg[it] = *(const half8_t*)(Kp + (size_t)(i >> 4) * HD + ((i & 15) << 3));
    vreg[it] = *(const half8_t*)(Vp + (size_t)(i & 63) * HD + (((i >> 6) << 3)));
  }
  // store tile 0
#pragma unroll
  for (int it = 0; it < 4; ++it) {
    int i = tid + it * 256;
    *(half8_t*)&Ks[i >> 4][(i & 15) << 3] = kreg[it];
    int k = i & 63, d0 = (i >> 6) << 3;
#pragma unroll
    for (int j = 0; j < 8; ++j) Vts[d0 + j][k] = vreg[it][j];
  }
  __syncthreads();

  for (int kt = 0; kt < nkt; ++kt) {
    const int k0 = kt * KTT;
    // prefetch next tile into registers (latency hidden behind compute)
    if (kt + 1 < nkt) {
      const int kn = k0 + KTT;
#pragma unroll
      for (int it = 0; it < 4; ++it) {
        int i = tid + it * 256;
        kreg[it] = *(const half8_t*)(Kp + (size_t)(kn + (i >> 4)) * HD + ((i & 15) << 3));
        vreg[it] = *(const half8_t*)(Vp + (size_t)(kn + (i & 63)) * HD + (((i >> 6) << 3)));
      }
    }

    if (k0 < wq_start + 32) {  // wave-uniform activity
      // ---- S^T = K Q^T : rows = kk, cols = qq (lane-owned) ----
      f32x16_t sc[2];
#pragma unroll
      for (int nt = 0; nt < 2; ++nt)
#pragma unroll
        for (int r = 0; r < 16; ++r) sc[nt][r] = 0.0f;
#pragma unroll
      for (int ks = 0; ks < 8; ++ks)
#pragma unroll
        for (int nt = 0; nt < 2; ++nt) {
          half8_t kf = *(const half8_t*)&Ks[nt * 32 + l31][ks * 16 + h32 * 8];
          sc[nt] = __builtin_amdgcn_mfma_f32_32x32x16_f16(kf, qfr[ks], sc[nt], 0, 0, 0);
        }
      // ---- scale + causal mask ----
      const bool needMask = (k0 + KTT > wq_start);
#pragma unroll
      for (int nt = 0; nt < 2; ++nt)
#pragma unroll
        for (int r = 0; r < 16; ++r) {
          int kg = k0 + nt * 32 + (r & 3) + 8 * (r >> 2) + 4 * h32;
          float s = sc[nt][r] * SCALE;
          sc[nt][r] = (!needMask || kg <= qq) ? s : -1.0e30f;
        }
      // ---- per-column online softmax (in-lane + one xor-32) ----
      float ml = sc[0][0];
#pragma unroll
      for (int r = 1; r < 16; ++r) ml = fmaxf(ml, sc[0][r]);
#pragma unroll
      for (int r = 0; r < 16; ++r) ml = fmaxf(ml, sc[1][r]);
      ml = fmaxf(ml, __shfl_xor(ml, 32));
      float mn = fmaxf(mrow, ml);
      float alpha = __builtin_amdgcn_exp2f(mrow - mn);
      mrow = mn;
      float ps = 0.0f;
#pragma unroll
      for (int nt = 0; nt < 2; ++nt)
#pragma unroll
        for (int r = 0; r < 16; ++r) {
          float p = __builtin_amdgcn_exp2f(sc[nt][r] - mn);
          sc[nt][r] = p;
          ps += p;
        }
      ps += __shfl_xor(ps, 32);
      lrow = lrow * alpha + ps;
#pragma unroll
      for (int dt = 0; dt < 4; ++dt)
#pragma unroll
        for (int r = 0; r < 16; ++r) o[dt][r] *= alpha;

      // ---- pack P^T to f16 pairs ----
      unsigned int pk[2][8];
#pragma unroll
      for (int nt = 0; nt < 2; ++nt)
#pragma unroll
        for (int gq = 0; gq < 8; ++gq)
          pk[nt][gq] = __builtin_bit_cast(
              unsigned int,
              __builtin_amdgcn_cvt_pkrtz(sc[nt][2 * gq], sc[nt][2 * gq + 1]));
      // ---- PV: O^T += V^T P^T  (B-frags via half-wave exchange) ----
#pragma unroll
      for (int ks2 = 0; ks2 < 4; ++ks2) {
        const int nt = ks2 >> 1, a = ks2 & 1;
        unsigned int own0 = hb ? pk[nt][4 * a + 2] : pk[nt][4 * a + 0];
        unsigned int own1 = hb ? pk[nt][4 * a + 3] : pk[nt][4 * a + 1];
        unsigned int oth0 = hb ? pk[nt][4 * a + 0] : pk[nt][4 * a + 2];
        unsigned int oth1 = hb ? pk[nt][4 * a + 1] : pk[nt][4 * a + 3];
        unsigned int rcv0 = __shfl_xor(oth0, 32);
        unsigned int rcv1 = __shfl_xor(oth1, 32);
        uint4_t fu;
        fu.x = hb ? rcv0 : own0;
        fu.y = hb ? rcv1 : own1;
        fu.z = hb ? own0 : rcv0;
        fu.w = hb ? own1 : rcv1;
        half8_t pf = __builtin_bit_cast(half8_t, fu);
#pragma unroll
        for (int dt = 0; dt < 4; ++dt) {
          half8_t vf = *(const half8_t*)&Vts[dt * 32 + l31][ks2 * 16 + h32 * 8];
          o[dt] = __builtin_amdgcn_mfma_f32_32x32x16_f16(vf, pf, o[dt], 0, 0, 0);
        }
      }
    }

    if (kt + 1 < nkt) {
      __syncthreads();  // everyone done reading Ks/Vts
#pragma unroll
      for (int it = 0; it < 4; ++it) {
        int i = tid + it * 256;
        *(half8_t*)&Ks[i >> 4][(i & 15) << 3] = kreg[it];
        int k = i & 63, d0 = (i >> 6) << 3;
#pragma unroll
        for (int j = 0; j < 8; ++j) Vts[d0 + j][k] = vreg[it][j];
      }
      __syncthreads();
    }
  }

  // ---- epilogue: O^T[d][qq] -> O[b][s][h*HD+d] via LDS transpose ----
  const float linv = 1.0f / lrow;
  const int s_l = tid >> 5, d_l = tid & 31;
#pragma unroll
  for (int dt = 0; dt < 4; ++dt) {
    __syncthreads();
#pragma unroll
    for (int gq = 0; gq < 4; ++gq) {
      float4 vv;
      vv.x = o[dt][4 * gq + 0] * linv;
      vv.y = o[dt][4 * gq + 1] * linv;
      vv.z = o[dt][4 * gq + 2] * linv;
      vv.w = o[dt][4 * gq + 3] * linv;
      *(float4*)&Ot[(w * 32 + l31) * 36 + 8 * gq + 4 * h32] = vv;
    }
    __syncthreads();
#pragma unroll
    for (int i = 0; i < 16; ++i) {
      int s = s_l + 8 * i;
      float v = Ot[s * 36 + d_l];
      O[((size_t)b * S_LEN + q0 + s) * DIM + h * HD + dt * 32 + d_l] = v;
    }
  }
}

// ---------------------------------------------------------------------------
extern "C" void kernel_launch(void* const* d_in, const int* in_sizes, int n_in,
                              void* d_out, int out_size, void* d_ws, size_t ws_size,
                              hipStream_t stream) {
  const float* x     = (const float*)d_in[0];
  const float* wq    = (const float*)d_in[1];
  const float* wk    = (const float*)d_in[2];
  const float* wv    = (const float*)d_in[3];
  const float* wo    = (const float*)d_in[4];
  const float* Sq    = (const float*)d_in[5];
  const float* Sk    = (const float*)d_in[6];
  const float* Sv    = (const float*)d_in[7];
  const float* So    = (const float*)d_in[8];
  const float* freqs = (const float*)d_in[9];
  float* out = (float*)d_out;

  const size_t AS_E = (size_t)2 * S_LEN * SKETCH;    // 262144
  const size_t SBQ_E = (size_t)2 * SKETCH * DIM;     // 262144
  const size_t SBK_E = (size_t)2 * SKETCH * KV_DIM;  // 131072

  float* fp = (float*)d_ws;
  float* ASq = fp;  fp += AS_E;
  float* ASk = fp;  fp += AS_E;
  float* ASv = fp;  fp += AS_E;
  float* ASo = fp;  fp += AS_E;
  float* SBq = fp;  fp += SBQ_E;
  float* SBk = fp;  fp += SBK_E;
  float* SBv = fp;  fp += SBK_E;
  float* SBo = fp;  fp += SBQ_E;
  float* ATT = fp;  fp += (size_t)2 * S_LEN * DIM;
  _Float16* hp = (_Float16*)fp;
  _Float16* Qfb = hp; hp += (size_t)2 * NH  * S_LEN * HD;
  _Float16* Kfb = hp; hp += (size_t)2 * NKV * S_LEN * HD;
  _Float16* Vfb = hp; hp += (size_t)2 * NKV * S_LEN * HD;

  // zero all atomic-accumulated buffers: 4 AS + 4 SB (contiguous)
  (void)hipMemsetAsync(ASq, 0, (4 * AS_E + 2 * SBQ_E + 2 * SBK_E) * sizeof(float), stream);

  hipLaunchKernelGGL(sbas_mfma, dim3(640), dim3(256), 0, stream,
                     x, Sq, Sk, Sv, So, wq, wk, wv, wo,
                     SBq, SBk, SBv, SBo, ASq, ASk, ASv);
  hipLaunchKernelGGL(proj_qkv, dim3(16, 64, 2), dim3(256), 0, stream,
                     ASq, ASk, ASv, SBq, SBk, SBv, freqs, Qfb, Kfb, Vfb);
  hipLaunchKernelGGL(attn_mfma, dim3(16, 32), dim3(256), 0, stream,
                     Qfb, Kfb, Vfb, ATT);
  hipLaunchKernelGGL(as_mfma, dim3(32, 8), dim3(256), 0, stream, ATT, So, ASo);
  hipLaunchKernelGGL(proj_out, dim3(16, 32, 2), dim3(256), 0, stream, ASo, SBo, out);
}